// Round 10
// baseline (215.296 us; speedup 1.0000x reference)
//
#include <hip/hip_runtime.h>
#include <math.h>

#define HEADS 6
#define SEQ   2048
#define DIM   768
#define HDIM  128
#define BATCH 4
#define MTOT  (BATCH*SEQ)   // 8192
#define NKV   (SEQ/32)      // 64

typedef float  f32x4   __attribute__((ext_vector_type(4)));
typedef float  f32x16  __attribute__((ext_vector_type(16)));
typedef __bf16 bf16x8  __attribute__((ext_vector_type(8)));
typedef __bf16 bf16x4  __attribute__((ext_vector_type(4)));
typedef float  f32x4v  __attribute__((ext_vector_type(4)));

typedef __attribute__((address_space(3))) void lds_v;
typedef __attribute__((address_space(1))) void gbl_v;

__device__ __forceinline__ f32x4 mfma16(bf16x8 a, bf16x8 b, f32x4 c) {
    return __builtin_amdgcn_mfma_f32_16x16x32_bf16(a, b, c, 0, 0, 0);
}
__device__ __forceinline__ f32x16 mfma32(bf16x8 a, bf16x8 b, f32x16 c) {
    return __builtin_amdgcn_mfma_f32_32x32x16_bf16(a, b, c, 0, 0, 0);
}
__device__ __forceinline__ unsigned int cvtpk(float lo, float hi) {
    unsigned int r;
    asm("v_cvt_pk_bf16_f32 %0, %1, %2" : "=v"(r) : "v"(lo), "v"(hi));
    return r;
}

// ---------------- cast x (f32 -> bf16) ----------------
__global__ __launch_bounds__(256) void cast_x_kernel(const float* __restrict__ x,
                                                     __bf16* __restrict__ xb) {
    int i = (blockIdx.x * 256 + threadIdx.x) * 4;
    f32x4v v = *(const f32x4v*)(x + i);
    bf16x4 o;
    o[0] = (__bf16)v[0]; o[1] = (__bf16)v[1];
    o[2] = (__bf16)v[2]; o[3] = (__bf16)v[3];
    *(bf16x4*)(xb + i) = o;
}

// ---------------- transpose weights W[k][n] f32 -> Wt[n][k] bf16 ----------------
__global__ __launch_bounds__(256) void transpose_w_kernel(
    const float* __restrict__ W0, const float* __restrict__ W1,
    const float* __restrict__ W2, const float* __restrict__ W3,
    __bf16* __restrict__ T0, __bf16* __restrict__ T1,
    __bf16* __restrict__ T2, __bf16* __restrict__ T3) {
    __shared__ float tile[32][33];
    const float* W; __bf16* T;
    if      (blockIdx.z == 0) { W = W0; T = T0; }
    else if (blockIdx.z == 1) { W = W1; T = T1; }
    else if (blockIdx.z == 2) { W = W2; T = T2; }
    else                      { W = W3; T = T3; }
    int n0 = blockIdx.x * 32, k0 = blockIdx.y * 32;
    int tx = threadIdx.x & 31, ty = threadIdx.x >> 5;
#pragma unroll
    for (int i = 0; i < 4; ++i)
        tile[ty + i*8][tx] = W[(size_t)(k0 + ty + i*8) * DIM + n0 + tx];
    __syncthreads();
#pragma unroll
    for (int i = 0; i < 4; ++i)
        T[(size_t)(n0 + ty + i*8) * DIM + k0 + tx] = (__bf16)tile[tx][ty + i*8];
}

// ============ GEMM core: triple-buffered LDS, 2-ahead prefetch, vmcnt(4) ============
#define GEMM_PIPE(A_PTR, B_PTR, NKSTEP)                                           \
    __shared__ __align__(16) __bf16 As[3][128 * 32];                              \
    __shared__ __align__(16) __bf16 Bs[3][128 * 32];                              \
    const int tid  = threadIdx.x;                                                 \
    const int wave = tid >> 6, lane = tid & 63;                                   \
    const int l16  = lane & 15, lh = lane >> 4;                                   \
    const int wr = wave >> 1, wc = wave & 1;                                      \
    f32x4 acc[4][4] = {};                                                         \
    auto stage = [&](int buf, int step) {                                         \
        const int k0 = step * 32;                                                 \
        _Pragma("unroll")                                                         \
        for (int ci = 0; ci < 4; ++ci) {                                          \
            int c = wave * 4 + ci;                                                \
            int t = c & 7;                                                        \
            int e = (t * 64 + lane) * 8;                                          \
            int r = e >> 5, kk = e & 31;                                          \
            const __bf16* gp = (c < 8) ? ((A_PTR) + (size_t)(m0 + r) * DIM + k0 + kk) \
                                       : ((B_PTR) + (size_t)(n0 + r) * DIM + k0 + kk); \
            __bf16* lp = (c < 8 ? As[buf] : Bs[buf]) + t * 512;                   \
            __builtin_amdgcn_global_load_lds((const gbl_v*)gp, (lds_v*)lp, 16, 0, 0); \
        }                                                                         \
    };                                                                            \
    stage(0, 0); stage(1, 1);                                                     \
    asm volatile("s_waitcnt vmcnt(4)" ::: "memory");                              \
    __builtin_amdgcn_s_barrier();                                                 \
    for (int t = 0; t < (NKSTEP); ++t) {                                          \
        const int cur = t % 3;                                                    \
        if (t + 2 < (NKSTEP)) stage((t + 2) % 3, t + 2);                          \
        bf16x8 af[4], bfr[4];                                                     \
        _Pragma("unroll")                                                         \
        for (int i = 0; i < 4; ++i)                                               \
            af[i] = *(const bf16x8*)&As[cur][(wr*64 + i*16 + l16) * 32 + lh*8];   \
        _Pragma("unroll")                                                         \
        for (int j = 0; j < 4; ++j)                                               \
            bfr[j] = *(const bf16x8*)&Bs[cur][(wc*64 + j*16 + l16) * 32 + lh*8];  \
        __builtin_amdgcn_s_setprio(1);                                            \
        _Pragma("unroll")                                                         \
        for (int i = 0; i < 4; ++i)                                               \
            _Pragma("unroll")                                                     \
            for (int j = 0; j < 4; ++j)                                           \
                acc[i][j] = mfma16(af[i], bfr[j], acc[i][j]);                     \
        __builtin_amdgcn_s_setprio(0);                                            \
        if (t + 2 < (NKSTEP))      asm volatile("s_waitcnt vmcnt(4)" ::: "memory"); \
        else if (t + 1 < (NKSTEP)) asm volatile("s_waitcnt vmcnt(0)" ::: "memory"); \
        __builtin_amdgcn_s_barrier();                                             \
    }

// ---------------- fused QKV GEMM: [8192,768] @ Wcat[2304,768]^T ----------------
__global__ __launch_bounds__(256) void gemm_qkv(const __bf16* __restrict__ A,
                                                const __bf16* __restrict__ Wcat,
                                                const float* __restrict__ bq,
                                                const float* __restrict__ bk,
                                                const float* __restrict__ bv,
                                                __bf16* __restrict__ Qb,
                                                __bf16* __restrict__ Kb,
                                                __bf16* __restrict__ Vt) {
    const int bn = blockIdx.x % (2304 / 128), bm = blockIdx.x / (2304 / 128);
    const int m0 = bm * 128, n0 = bn * 128;
    GEMM_PIPE(A, Wcat, 24)

    const int sel = n0 / DIM;                 // 0=Q 1=K 2=V (block-uniform)
    const float* bias = sel == 0 ? bq : (sel == 1 ? bk : bv);
#pragma unroll
    for (int i = 0; i < 4; ++i) {
        int row = m0 + wr*64 + i*16 + lh*4;
#pragma unroll
        for (int j = 0; j < 4; ++j) {
            int col  = n0 + wc*64 + j*16 + l16;
            int lcol = col - sel * DIM;
            float bvv = bias[lcol];
            if (sel < 2) {
                __bf16* o = (sel == 0) ? Qb : Kb;
#pragma unroll
                for (int r = 0; r < 4; ++r)
                    o[(size_t)(row + r) * DIM + lcol] = (__bf16)(acc[i][j][r] + bvv);
            } else {
                int bb = row >> 11, ll = row & (SEQ - 1);
                int hh = lcol >> 7, dd = lcol & (HDIM - 1);
                bf16x4 pk;
#pragma unroll
                for (int r = 0; r < 4; ++r) pk[r] = (__bf16)(acc[i][j][r] + bvv);
                *(bf16x4*)&Vt[((size_t)((bb*HEADS + hh) * HDIM + dd)) * SEQ + ll] = pk;
            }
        }
    }
}

// ---------------- out-proj GEMM: [8192,768] @ Wto[768,768]^T -> f32 ----------------
__global__ __launch_bounds__(256) void gemm_out(const __bf16* __restrict__ A,
                                                const __bf16* __restrict__ Bt,
                                                const float* __restrict__ bias,
                                                float* __restrict__ outp) {
    const int bn = blockIdx.x % (DIM / 128), bm = blockIdx.x / (DIM / 128);
    const int m0 = bm * 128, n0 = bn * 128;
    GEMM_PIPE(A, Bt, 24)

#pragma unroll
    for (int i = 0; i < 4; ++i) {
        int row = m0 + wr*64 + i*16 + lh*4;
#pragma unroll
        for (int j = 0; j < 4; ++j) {
            int col = n0 + wc*64 + j*16 + l16;
            float bv = bias[col];
#pragma unroll
            for (int r = 0; r < 4; ++r)
                outp[(size_t)(row + r) * DIM + col] = acc[i][j][r] + bv;
        }
    }
}

// ---------------- flash attention: r8 structure + chain-split QK + tree reduce ----
// 4 waves x 32 q = 128-q tiles. K+V triple-buffered LDS via global_load_lds,
// 1-ahead prefetch, ONE barrier/iter, vmcnt(4) (stage(i) covered by full iter).
// CHANGES vs r8 (A/B on dependency-chain hypothesis):
//   (1) QK^T split into two independent 4-deep MFMA chains (even/odd k-chunks),
//       combined with one elementwise f32x16 add - chain depth 8 -> 4.
//   (2) max/sum reductions as explicit pairwise trees - depth 15 -> 4.
// Swapped QK^T 32x32; in-register softmax + defer-max; P via cvt_pk+permlane;
// PV -> O^T (4 independent chains). Causal mask: key <= q+1 (tril k=1).
__global__ __launch_bounds__(256, 3) void attn_kernel(
    const __bf16* __restrict__ Q, const __bf16* __restrict__ K,
    const __bf16* __restrict__ Vt,
    __bf16* __restrict__ po, float* __restrict__ pm, float* __restrict__ pl,
    __bf16* __restrict__ Ob, int ks) {
    __shared__ __align__(16) __bf16 Ks[3][32 * 128];
    __shared__ __align__(16) __bf16 Vs[3][128 * 32];
    const int lane = threadIdx.x & 63, wv = threadIdx.x >> 6;   // wv 0..3
    const int l32 = lane & 31, hi = lane >> 5;
    // grid: 8 xcd x 3 bh_l x (16 tiles x ks)  -> bh pinned to XCD
    const int id  = blockIdx.x;
    const int xcd = id & 7;
    const int idx = id >> 3;
    const int bh_l = idx % 3, rem = idx / 3;
    const int c = rem % ks, tl = rem / ks;                      // tl 0..15
    const int tile = (tl & 1) ? (15 - (tl >> 1)) : (tl >> 1);   // heavy/light mix
    const int bh = xcd + 8 * bh_l;
    const int b = bh / HEADS, h = bh - b * HEADS;
    const int qw0 = tile * 128 + wv * 32;                       // wave's first q row
    const float qs = 0.12751674770951932f;  // 1/sqrt(128) * log2(e)

    // Q B-frags: col=q=lane&31, k = 8*hi + e, 8 chunks over D=128
    bf16x8 qfr[8];
    {
        const __bf16* qp = Q + (size_t)(b*SEQ + qw0 + l32) * DIM + h*HDIM + hi*8;
#pragma unroll
        for (int cc = 0; cc < 8; ++cc) {
            bf16x8 v = *(const bf16x8*)(qp + cc*16);
            bf16x8 sv;
#pragma unroll
            for (int e = 0; e < 8; ++e) sv[e] = (__bf16)((float)v[e] * qs);
            qfr[cc] = sv;
        }
    }

    const __bf16* kgb = K  + (size_t)(b*SEQ) * DIM + h*HDIM;
    const __bf16* vgb = Vt + (size_t)bh * HDIM * SEQ;

    // stage one k-block: K 32x128 (8 instrs) + V 128x32 (8 instrs), 4/wave
    auto stage = [&](int buf, int kb) {
        const int kbase = kb * 32;
#pragma unroll
        for (int s = 0; s < 2; ++s) {
            const int j = wv * 2 + s;              // 0..7, wave-uniform
            const int row = j * 4 + (lane >> 4);
            const int c16 = (lane & 15) ^ (row & 7);
            const __bf16* gp = kgb + (size_t)(kbase + row) * DIM + c16 * 8;
            __builtin_amdgcn_global_load_lds((const gbl_v*)gp,
                (lds_v*)&Ks[buf][j * 512], 16, 0, 0);
        }
#pragma unroll
        for (int s = 0; s < 2; ++s) {
            const int j = wv * 2 + s;              // 0..7, wave-uniform
            const int row = j * 16 + (lane >> 2);  // d-row 0..127
            const int c4 = (lane & 3) ^ ((row >> 1) & 3);
            const __bf16* gp = vgb + (size_t)row * SEQ + kbase + c4 * 8;
            __builtin_amdgcn_global_load_lds((const gbl_v*)gp,
                (lds_v*)&Vs[buf][j * 512], 16, 0, 0);
        }
    };

    f32x16 o[4] = {};                          // O^T accum: 4 d-blocks of 32
    float mx = -INFINITY, lsum = 0.f;
    const int nkb = min(4 * tile + 5, NKV);
    const int cnt = (nkb - c + ks - 1) / ks;

    stage(0, c);
    for (int i = 0; i < cnt; ++i) {
        const int kb = c + i * ks;
        const int kbase = kb * 32;
        const int cur = i % 3;
        if (i + 1 < cnt) {
            stage((i + 1) % 3, kb + ks);
            asm volatile("s_waitcnt vmcnt(4)" ::: "memory");   // stage(i) landed
        } else {
            asm volatile("s_waitcnt vmcnt(0)" ::: "memory");
        }
        __builtin_amdgcn_s_barrier();          // all waves' stage(i) published

        if (kbase <= qw0 + 32) {               // wave-uniform activity test
            // QK^T: two INDEPENDENT 4-deep chains (even/odd k-chunks), interleaved
            bf16x8 kf[8];
#pragma unroll
            for (int cc = 0; cc < 8; ++cc) {
                const int c8 = ((cc << 1) | hi) ^ (l32 & 7);   // swizzled slot
                kf[cc] = *(const bf16x8*)&Ks[cur][l32 * 128 + c8 * 8];
            }
            f32x16 sa = {}, sb = {};
            __builtin_amdgcn_s_setprio(1);
#pragma unroll
            for (int cc = 0; cc < 4; ++cc) {
                sa = mfma32(kf[2*cc],     qfr[2*cc],     sa);
                sb = mfma32(kf[2*cc + 1], qfr[2*cc + 1], sb);
            }
            __builtin_amdgcn_s_setprio(0);
            // V A-frags from LDS: row=d=db*32+l32, chunk u=kc*2+hi swizzled
            bf16x8 vf[8];
#pragma unroll
            for (int db = 0; db < 4; ++db)
#pragma unroll
                for (int kc = 0; kc < 2; ++kc) {
                    const int row = db * 32 + l32;
                    const int u = ((kc*2 + hi) ^ ((row >> 1) & 3));
                    vf[db*2 + kc] = *(const bf16x8*)&Vs[cur][row * 32 + u * 8];
                }

            float p[16];
#pragma unroll
            for (int r = 0; r < 16; ++r) p[r] = sa[r] + sb[r];   // combine chains
            if (kbase + 30 > qw0) {            // diagonal: apply causal mask
                const int q1 = qw0 + l32 + 1;
#pragma unroll
                for (int r = 0; r < 16; ++r) {
                    const int key = kbase + (r & 3) + 8*(r >> 2) + 4*hi;
                    if (key > q1) p[r] = -INFINITY;
                }
            }
            // max: explicit pairwise tree (depth 4)
            float t8[8], t4[4], t2[2];
#pragma unroll
            for (int r = 0; r < 8; ++r) t8[r] = fmaxf(p[r], p[r + 8]);
#pragma unroll
            for (int r = 0; r < 4; ++r) t4[r] = fmaxf(t8[r], t8[r + 4]);
            t2[0] = fmaxf(t4[0], t4[2]); t2[1] = fmaxf(t4[1], t4[3]);
            float m0 = fmaxf(t2[0], t2[1]);
            m0 = fmaxf(m0, __shfl_xor(m0, 32));
            // defer-max: skip rescale while growth <= 8 (log2 domain)
            const bool defer = __all(m0 <= mx + 8.f && mx > -3e38f);
            if (!defer) {
                const float mnew = fmaxf(mx, m0);
                const float resc = (mx < mnew) ? exp2f(mx - mnew) : 1.0f;
                lsum *= resc;
#pragma unroll
                for (int db = 0; db < 4; ++db)
#pragma unroll
                    for (int r = 0; r < 16; ++r) o[db][r] *= resc;
                mx = mnew;
            }
            const float mref = (mx == -INFINITY) ? 0.f : mx;   // all-masked guard
#pragma unroll
            for (int r = 0; r < 16; ++r) p[r] = exp2f(p[r] - mref);
            // sum: explicit pairwise tree (depth 4)
            float s8[8], s4[4];
#pragma unroll
            for (int r = 0; r < 8; ++r) s8[r] = p[r] + p[r + 8];
#pragma unroll
            for (int r = 0; r < 4; ++r) s4[r] = s8[r] + s8[r + 4];
            float rs = (s4[0] + s4[2]) + (s4[1] + s4[3]);
            rs += __shfl_xor(rs, 32);
            lsum += rs;
            // P -> bf16 B-frags via cvt_pk + permlane32_swap
            union { unsigned int u[4]; bf16x8 v; } pw[2];
#pragma unroll
            for (int kc = 0; kc < 2; ++kc) {
                unsigned int X = cvtpk(p[8*kc + 0], p[8*kc + 1]);
                unsigned int Y = cvtpk(p[8*kc + 4], p[8*kc + 5]);
                asm("v_permlane32_swap_b32 %0, %1" : "+v"(X), "+v"(Y));
                unsigned int X2 = cvtpk(p[8*kc + 2], p[8*kc + 3]);
                unsigned int Y2 = cvtpk(p[8*kc + 6], p[8*kc + 7]);
                asm("v_permlane32_swap_b32 %0, %1" : "+v"(X2), "+v"(Y2));
                pw[kc].u[0] = X; pw[kc].u[1] = X2; pw[kc].u[2] = Y; pw[kc].u[3] = Y2;
            }
            __builtin_amdgcn_s_setprio(1);
#pragma unroll
            for (int db = 0; db < 4; ++db) {    // 4 independent 2-deep chains
                o[db] = mfma32(vf[db*2 + 0], pw[0].v, o[db]);
                o[db] = mfma32(vf[db*2 + 1], pw[1].v, o[db]);
            }
            __builtin_amdgcn_s_setprio(0);
        }
    }

    // write-out: lane holds q = qw0+l32 (col), d = db*32 + (reg&3)+8*(reg>>2)+4*hi
    if (ks == 1) {
        const float inv = 1.0f / lsum;
        __bf16* op = Ob + (size_t)(b*SEQ + qw0 + l32) * DIM + h*HDIM + hi*4;
#pragma unroll
        for (int db = 0; db < 4; ++db)
#pragma unroll
            for (int g = 0; g < 4; ++g) {
                bf16x4 pk;
#pragma unroll
                for (int r = 0; r < 4; ++r) pk[r] = (__bf16)(o[db][g*4 + r] * inv);
                *(bf16x4*)(op + db*32 + g*8) = pk;
            }
    } else {
        const int pid = (bh * 16 + tile) * ks + c;
        const int lq  = wv * 32 + l32;         // 0..127
        __bf16* pop = po + ((size_t)pid * 128 + lq) * HDIM + hi*4;
#pragma unroll
        for (int db = 0; db < 4; ++db)
#pragma unroll
            for (int g = 0; g < 4; ++g) {
                bf16x4 pk;
#pragma unroll
                for (int r = 0; r < 4; ++r) pk[r] = (__bf16)o[db][g*4 + r];
                *(bf16x4*)(pop + db*32 + g*8) = pk;
            }
        if (hi == 0) {
            pm[(size_t)pid * 128 + lq] = mx;
            pl[(size_t)pid * 128 + lq] = lsum;
        }
    }
}

// ---------------- merge split-K partials (128-row tiles) ----------------
__global__ __launch_bounds__(256) void merge_kernel(const __bf16* __restrict__ po,
    const float* __restrict__ pm, const float* __restrict__ pl,
    __bf16* __restrict__ Ob, int ks) {
    const int id = blockIdx.x;             // bh*16 + tile
    const int bh = id >> 4, tile = id & 15;
    const int b = bh / HEADS, h = bh - b * HEADS;
    const int lq = threadIdx.x >> 1;       // 0..127
    const int d0 = (threadIdx.x & 1) * 64;
    const int pb = id * ks;
    float M = -INFINITY;
    for (int cc = 0; cc < ks; ++cc) M = fmaxf(M, pm[(size_t)(pb + cc) * 128 + lq]);
    float L = 0.f, w[2] = {0.f, 0.f};
    for (int cc = 0; cc < ks; ++cc) {
        w[cc] = exp2f(pm[(size_t)(pb + cc) * 128 + lq] - M);
        L += w[cc] * pl[(size_t)(pb + cc) * 128 + lq];
    }
    const float invL = 1.0f / L;
    __bf16* op = Ob + (size_t)(b*SEQ + tile*128 + lq) * DIM + h*HDIM;
#pragma unroll
    for (int d = 0; d < 64; d += 8) {
        float acc[8] = {};
        for (int cc = 0; cc < ks; ++cc) {
            bf16x8 v = *(const bf16x8*)&po[((size_t)(pb + cc) * 128 + lq) * HDIM + d0 + d];
            const float wc = w[cc];
#pragma unroll
            for (int e = 0; e < 8; ++e) acc[e] += wc * (float)v[e];
        }
        bf16x8 ov;
#pragma unroll
        for (int e = 0; e < 8; ++e) ov[e] = (__bf16)(acc[e] * invL);
        *(bf16x8*)(op + d0 + d) = ov;
    }
}

// ---------------- launch ----------------
extern "C" void kernel_launch(void* const* d_in, const int* in_sizes, int n_in,
                              void* d_out, int out_size, void* d_ws, size_t ws_size,
                              hipStream_t stream) {
    const float* x  = (const float*)d_in[0];
    const float* Wq = (const float*)d_in[1];
    const float* bq = (const float*)d_in[2];
    const float* Wk = (const float*)d_in[3];
    const float* bk = (const float*)d_in[4];
    const float* Wv = (const float*)d_in[5];
    const float* bv = (const float*)d_in[6];
    const float* Wo = (const float*)d_in[7];
    const float* bo = (const float*)d_in[8];

    char* p = (char*)d_ws;
    const size_t SZ_X = (size_t)MTOT * DIM * 2;        // 12.6 MB
    const size_t SZ_W = (size_t)DIM * DIM * 2;         // 1.18 MB
    __bf16* xb   = (__bf16*)p; p += SZ_X;
    __bf16* Wcat = (__bf16*)p; p += 3 * SZ_W;          // [2304][768]
    __bf16* Wto  = (__bf16*)p; p += SZ_W;
    __bf16* Qb   = (__bf16*)p; p += SZ_X;
    __bf16* Kb   = (__bf16*)p; p += SZ_X;
    __bf16* Vt   = (__bf16*)p; p += SZ_X;
    __bf16* Ob   = (__bf16*)p; p += SZ_X;

    const size_t base = (size_t)(p - (char*)d_ws);
    const size_t SZ_PO = (size_t)24 * 16 * 2 * 128 * HDIM * 2;  // 25.2 MB (ks=2)
    const size_t SZ_PM = (size_t)24 * 16 * 2 * 128 * 4;         // 0.39 MB
    const int ks = (ws_size >= base + SZ_PO + 2 * SZ_PM) ? 2 : 1;
    __bf16* po = (__bf16*)p;            p += SZ_PO;
    float*  pmv = (float*)p;            p += SZ_PM;
    float*  plv = (float*)p;

    cast_x_kernel<<<(MTOT * DIM) / 1024, 256, 0, stream>>>(x, xb);
    transpose_w_kernel<<<dim3(DIM/32, DIM/32, 4), 256, 0, stream>>>(
        Wq, Wk, Wv, Wo,
        Wcat, Wcat + (size_t)DIM*DIM, Wcat + (size_t)2*DIM*DIM, Wto);

    gemm_qkv<<<(MTOT/128) * (2304/128), 256, 0, stream>>>(xb, Wcat, bq, bk, bv, Qb, Kb, Vt);

    attn_kernel<<<8 * 3 * 16 * ks, 256, 0, stream>>>(Qb, Kb, Vt, po, pmv, plv, Ob, ks);
    if (ks == 2)
        merge_kernel<<<24 * 16, 256, 0, stream>>>(po, pmv, plv, Ob, ks);

    gemm_out<<<(MTOT/128) * (DIM/128), 256, 0, stream>>>(Ob, Wto, bo, (float*)d_out);
}

// Round 11
// 179.343 us; speedup vs baseline: 1.2005x; 1.2005x over previous
//
#include <hip/hip_runtime.h>
#include <math.h>

#define HEADS 6
#define SEQ   2048
#define DIM   768
#define HDIM  128
#define BATCH 4
#define MTOT  (BATCH*SEQ)   // 8192
#define NKV   (SEQ/32)      // 64

typedef float  f32x4   __attribute__((ext_vector_type(4)));
typedef __bf16 bf16x8  __attribute__((ext_vector_type(8)));
typedef __bf16 bf16x4  __attribute__((ext_vector_type(4)));
typedef float  f32x4v  __attribute__((ext_vector_type(4)));

typedef __attribute__((address_space(3))) void lds_v;
typedef __attribute__((address_space(1))) void gbl_v;

__device__ __forceinline__ f32x4 mfma16(bf16x8 a, bf16x8 b, f32x4 c) {
    return __builtin_amdgcn_mfma_f32_16x16x32_bf16(a, b, c, 0, 0, 0);
}
__device__ __forceinline__ unsigned int bperm(int srclane, unsigned int v) {
    return (unsigned int)__builtin_amdgcn_ds_bpermute(srclane << 2, (int)v);
}
__device__ __forceinline__ unsigned int pack2(float lo, float hi) {
    union { __bf16 b; unsigned short u; } a, c;
    a.b = (__bf16)lo; c.b = (__bf16)hi;
    return ((unsigned int)c.u << 16) | (unsigned int)a.u;
}

// ---------------- cast x (f32 -> bf16) ----------------
__global__ __launch_bounds__(256) void cast_x_kernel(const float* __restrict__ x,
                                                     __bf16* __restrict__ xb) {
    int i = (blockIdx.x * 256 + threadIdx.x) * 4;
    f32x4v v = *(const f32x4v*)(x + i);
    bf16x4 o;
    o[0] = (__bf16)v[0]; o[1] = (__bf16)v[1];
    o[2] = (__bf16)v[2]; o[3] = (__bf16)v[3];
    *(bf16x4*)(xb + i) = o;
}

// ---------------- transpose weights W[k][n] f32 -> Wt[n][k] bf16 ----------------
__global__ __launch_bounds__(256) void transpose_w_kernel(
    const float* __restrict__ W0, const float* __restrict__ W1,
    const float* __restrict__ W2, const float* __restrict__ W3,
    __bf16* __restrict__ T0, __bf16* __restrict__ T1,
    __bf16* __restrict__ T2, __bf16* __restrict__ T3) {
    __shared__ float tile[32][33];
    const float* W; __bf16* T;
    if      (blockIdx.z == 0) { W = W0; T = T0; }
    else if (blockIdx.z == 1) { W = W1; T = T1; }
    else if (blockIdx.z == 2) { W = W2; T = T2; }
    else                      { W = W3; T = T3; }
    int n0 = blockIdx.x * 32, k0 = blockIdx.y * 32;
    int tx = threadIdx.x & 31, ty = threadIdx.x >> 5;
#pragma unroll
    for (int i = 0; i < 4; ++i)
        tile[ty + i*8][tx] = W[(size_t)(k0 + ty + i*8) * DIM + n0 + tx];
    __syncthreads();
#pragma unroll
    for (int i = 0; i < 4; ++i)
        T[(size_t)(n0 + ty + i*8) * DIM + k0 + tx] = (__bf16)tile[tx][ty + i*8];
}

// ============ GEMM core: triple-buffered LDS, 2-ahead prefetch, vmcnt(4) ============
#define GEMM_PIPE(A_PTR, B_PTR, NKSTEP)                                           \
    __shared__ __align__(16) __bf16 As[3][128 * 32];                              \
    __shared__ __align__(16) __bf16 Bs[3][128 * 32];                              \
    const int tid  = threadIdx.x;                                                 \
    const int wave = tid >> 6, lane = tid & 63;                                   \
    const int l16  = lane & 15, lh = lane >> 4;                                   \
    const int wr = wave >> 1, wc = wave & 1;                                      \
    f32x4 acc[4][4] = {};                                                         \
    auto stage = [&](int buf, int step) {                                         \
        const int k0 = step * 32;                                                 \
        _Pragma("unroll")                                                         \
        for (int ci = 0; ci < 4; ++ci) {                                          \
            int c = wave * 4 + ci;                                                \
            int t = c & 7;                                                        \
            int e = (t * 64 + lane) * 8;                                          \
            int r = e >> 5, kk = e & 31;                                          \
            const __bf16* gp = (c < 8) ? ((A_PTR) + (size_t)(m0 + r) * DIM + k0 + kk) \
                                       : ((B_PTR) + (size_t)(n0 + r) * DIM + k0 + kk); \
            __bf16* lp = (c < 8 ? As[buf] : Bs[buf]) + t * 512;                   \
            __builtin_amdgcn_global_load_lds((const gbl_v*)gp, (lds_v*)lp, 16, 0, 0); \
        }                                                                         \
    };                                                                            \
    stage(0, 0); stage(1, 1);                                                     \
    asm volatile("s_waitcnt vmcnt(4)" ::: "memory");                              \
    __builtin_amdgcn_s_barrier();                                                 \
    for (int t = 0; t < (NKSTEP); ++t) {                                          \
        const int cur = t % 3;                                                    \
        if (t + 2 < (NKSTEP)) stage((t + 2) % 3, t + 2);                          \
        bf16x8 af[4], bfr[4];                                                     \
        _Pragma("unroll")                                                         \
        for (int i = 0; i < 4; ++i)                                               \
            af[i] = *(const bf16x8*)&As[cur][(wr*64 + i*16 + l16) * 32 + lh*8];   \
        _Pragma("unroll")                                                         \
        for (int j = 0; j < 4; ++j)                                               \
            bfr[j] = *(const bf16x8*)&Bs[cur][(wc*64 + j*16 + l16) * 32 + lh*8];  \
        __builtin_amdgcn_s_setprio(1);                                            \
        _Pragma("unroll")                                                         \
        for (int i = 0; i < 4; ++i)                                               \
            _Pragma("unroll")                                                     \
            for (int j = 0; j < 4; ++j)                                           \
                acc[i][j] = mfma16(af[i], bfr[j], acc[i][j]);                     \
        __builtin_amdgcn_s_setprio(0);                                            \
        if (t + 2 < (NKSTEP))      asm volatile("s_waitcnt vmcnt(4)" ::: "memory"); \
        else if (t + 1 < (NKSTEP)) asm volatile("s_waitcnt vmcnt(0)" ::: "memory"); \
        __builtin_amdgcn_s_barrier();                                             \
    }

// ---------------- fused QKV GEMM: [8192,768] @ Wcat[2304,768]^T ----------------
__global__ __launch_bounds__(256) void gemm_qkv(const __bf16* __restrict__ A,
                                                const __bf16* __restrict__ Wcat,
                                                const float* __restrict__ bq,
                                                const float* __restrict__ bk,
                                                const float* __restrict__ bv,
                                                __bf16* __restrict__ Qb,
                                                __bf16* __restrict__ Kb,
                                                __bf16* __restrict__ Vt) {
    const int bn = blockIdx.x % (2304 / 128), bm = blockIdx.x / (2304 / 128);
    const int m0 = bm * 128, n0 = bn * 128;
    GEMM_PIPE(A, Wcat, 24)

    const int sel = n0 / DIM;                 // 0=Q 1=K 2=V (block-uniform)
    const float* bias = sel == 0 ? bq : (sel == 1 ? bk : bv);
#pragma unroll
    for (int i = 0; i < 4; ++i) {
        int row = m0 + wr*64 + i*16 + lh*4;
#pragma unroll
        for (int j = 0; j < 4; ++j) {
            int col  = n0 + wc*64 + j*16 + l16;
            int lcol = col - sel * DIM;
            float bvv = bias[lcol];
            if (sel < 2) {
                __bf16* o = (sel == 0) ? Qb : Kb;
#pragma unroll
                for (int r = 0; r < 4; ++r)
                    o[(size_t)(row + r) * DIM + lcol] = (__bf16)(acc[i][j][r] + bvv);
            } else {
                int bb = row >> 11, ll = row & (SEQ - 1);
                int hh = lcol >> 7, dd = lcol & (HDIM - 1);
                bf16x4 pk;
#pragma unroll
                for (int r = 0; r < 4; ++r) pk[r] = (__bf16)(acc[i][j][r] + bvv);
                *(bf16x4*)&Vt[((size_t)((bb*HEADS + hh) * HDIM + dd)) * SEQ + ll] = pk;
            }
        }
    }
}

// ---------------- out-proj GEMM: [8192,768] @ Wto[768,768]^T -> f32 ----------------
__global__ __launch_bounds__(256) void gemm_out(const __bf16* __restrict__ A,
                                                const __bf16* __restrict__ Bt,
                                                const float* __restrict__ bias,
                                                float* __restrict__ outp) {
    const int bn = blockIdx.x % (DIM / 128), bm = blockIdx.x / (DIM / 128);
    const int m0 = bm * 128, n0 = bn * 128;
    GEMM_PIPE(A, Bt, 24)

#pragma unroll
    for (int i = 0; i < 4; ++i) {
        int row = m0 + wr*64 + i*16 + lh*4;
#pragma unroll
        for (int j = 0; j < 4; ++j) {
            int col = n0 + wc*64 + j*16 + l16;
            float bv = bias[col];
#pragma unroll
            for (int r = 0; r < 4; ++r)
                outp[(size_t)(row + r) * DIM + col] = acc[i][j][r] + bv;
        }
    }
}

// ---------------- flash attention (r3-verbatim, measured 94 us) ----------------
// Block = 4 waves x 16 q-rows = 64 q-rows. Chunk c handles k-blocks kb ≡ c (mod ks).
// K/V double-buffered in LDS via global_load_lds with XOR-swizzled source.
// Swapped QK^T (s = mfma(K,Q)); softmax in-register; P via ds_bpermute;
// PV computes O^T (o = mfma(V^T, P)). Causal mask: key <= q+1 (tril k=1).
__global__ __launch_bounds__(256, 3) void attn_kernel(
    const __bf16* __restrict__ Q, const __bf16* __restrict__ K,
    const __bf16* __restrict__ Vt,
    __bf16* __restrict__ po, float* __restrict__ pm, float* __restrict__ pl,
    __bf16* __restrict__ Ob, int ks) {
    __shared__ __align__(16) __bf16 Ks[2][32 * 128];
    __shared__ __align__(16) __bf16 Vs[2][128 * 32];
    const int lane = threadIdx.x & 63, wv = threadIdx.x >> 6;
    const int l16 = lane & 15, lh = lane >> 4;
    // grid: 8 xcd x 3 bh_l x 32 tl x ks  -> bh pinned to XCD (blockIdx % 8)
    const int id  = blockIdx.x;
    const int xcd = id & 7;
    const int idx = id >> 3;
    const int bh_l = idx % 3, rem = idx / 3;
    const int c = rem % ks, tl = rem / ks;
    const int tile = (tl & 1) ? (31 - (tl >> 1)) : (tl >> 1);   // heavy/light mix
    const int bh = xcd + 8 * bh_l;
    const int b = bh / HEADS, h = bh - b * HEADS;
    const int qw0 = tile * 64 + wv * 16;
    const float qs = 0.12751674770951932f;  // 1/sqrt(128) * log2(e)

    bf16x8 qf[4];
    {
        const __bf16* qp = Q + (size_t)(b*SEQ + qw0 + l16) * DIM + h*HDIM + lh*8;
#pragma unroll
        for (int kk = 0; kk < 4; ++kk) {
            bf16x8 v = *(const bf16x8*)(qp + kk*32);
            bf16x8 sv;
#pragma unroll
            for (int e = 0; e < 8; ++e) sv[e] = (__bf16)((float)v[e] * qs);
            qf[kk] = sv;
        }
    }

    const __bf16* kgb = K  + (size_t)(b*SEQ) * DIM + h*HDIM;
    const __bf16* vgb = Vt + (size_t)bh * HDIM * SEQ;

    // stage one k-block (K: 32x128 swizzled, V: 128x32 swizzled) -> 16 lds-loads/4 waves
    auto stage = [&](int buf, int kb) {
        const int kbase = kb * 32;
#pragma unroll
        for (int s = 0; s < 4; ++s) {
            const int j = wv * 4 + s;          // wave-uniform
            if (j < 8) {
                const int row = j * 4 + (lane >> 4);
                const int c16 = (lane & 15) ^ (row & 7);      // pre-swizzled source
                const __bf16* gp = kgb + (size_t)(kbase + row) * DIM + c16 * 8;
                __builtin_amdgcn_global_load_lds((const gbl_v*)gp,
                    (lds_v*)&Ks[buf][j * 512], 16, 0, 0);
            } else {
                const int jj = j - 8;
                const int row = jj * 16 + (lane >> 2);
                const int c16 = (lane & 3) ^ ((row >> 1) & 3);
                const __bf16* gp = vgb + (size_t)row * SEQ + kbase + c16 * 8;
                __builtin_amdgcn_global_load_lds((const gbl_v*)gp,
                    (lds_v*)&Vs[buf][jj * 512], 16, 0, 0);
            }
        }
    };

    f32x4 o[8] = {};
    float mx = -INFINITY, lsum = 0.f;
    const int nkb = min(2 * tile + 3, NKV);
    const int cnt = (nkb - c + ks - 1) / ks;

    stage(0, c);
    asm volatile("s_waitcnt vmcnt(0)" ::: "memory");
    __builtin_amdgcn_s_barrier();

    int cur = 0;
    for (int i = 0; i < cnt; ++i) {
        const int kb = c + i * ks;
        const int kbase = kb * 32;
        const bool more = (i + 1 < cnt);       // block-uniform
        if (more) {
            stage(cur ^ 1, kb + ks);
            asm volatile("s_waitcnt vmcnt(4)" ::: "memory");  // prev stage done, next in flight
        } else {
            asm volatile("s_waitcnt vmcnt(0)" ::: "memory");
        }
        __builtin_amdgcn_s_barrier();          // buf[cur] valid for all waves

        if (kbase <= qw0 + 16) {               // wave-uniform activity test
            bf16x8 kfA[4], kfB[4];
#pragma unroll
            for (int kk = 0; kk < 4; ++kk) {
                const int ca = (kk*4 + lh) ^ (l16 & 7);
                kfA[kk] = *(const bf16x8*)&Ks[cur][l16 * 128 + ca * 8];
                const int rb = 16 + l16;
                const int cb = (kk*4 + lh) ^ (rb & 7);
                kfB[kk] = *(const bf16x8*)&Ks[cur][rb * 128 + cb * 8];
            }
            f32x4 sA = {}, sB = {};
            __builtin_amdgcn_s_setprio(1);
#pragma unroll
            for (int kk = 0; kk < 4; ++kk) {
                sA = mfma16(kfA[kk], qf[kk], sA);
                sB = mfma16(kfB[kk], qf[kk], sB);
            }
            __builtin_amdgcn_s_setprio(0);
            const int q = qw0 + l16;
            float p[8];
#pragma unroll
            for (int r = 0; r < 4; ++r) { p[r] = sA[r]; p[r+4] = sB[r]; }
            if (kbase + 30 > qw0) {            // diagonal: apply causal mask
#pragma unroll
                for (int r = 0; r < 4; ++r) {
                    const int key = kbase + lh*4 + r;
                    if (key      > q + 1) p[r]   = -INFINITY;
                    if (key + 16 > q + 1) p[r+4] = -INFINITY;
                }
            }
            float m0 = p[0];
#pragma unroll
            for (int t2 = 1; t2 < 8; ++t2) m0 = fmaxf(m0, p[t2]);
            m0 = fmaxf(m0, __shfl_xor(m0, 16));
            m0 = fmaxf(m0, __shfl_xor(m0, 32));
            const float mnew = fmaxf(mx, m0);
            const bool grow = m0 > mx;
            const float mref = (mnew == -INFINITY) ? 0.f : mnew;  // NaN guard (split-K)
#pragma unroll
            for (int t2 = 0; t2 < 8; ++t2) p[t2] = exp2f(p[t2] - mref);
            float rs = 0.f;
#pragma unroll
            for (int t2 = 0; t2 < 8; ++t2) rs += p[t2];
            rs += __shfl_xor(rs, 16);
            rs += __shfl_xor(rs, 32);
            if (__any(grow)) {
                const float resc = (mx < mnew) ? exp2f(mx - mnew) : 1.0f;  // NaN guard
                lsum = lsum * resc + rs;
                mx = mnew;
#pragma unroll
                for (int d = 0; d < 8; ++d)
#pragma unroll
                    for (int r = 0; r < 4; ++r) o[d][r] *= resc;
            } else {
                lsum += rs;
            }
            unsigned int w0 = pack2(p[0], p[1]);
            unsigned int w1 = pack2(p[2], p[3]);
            unsigned int w2 = pack2(p[4], p[5]);
            unsigned int w3 = pack2(p[6], p[7]);
            const int s0l = l16 + ((lh & 1) << 5);
            unsigned int A0 = bperm(s0l,      w0), A1 = bperm(s0l,      w1);
            unsigned int A2 = bperm(s0l,      w2), A3 = bperm(s0l,      w3);
            unsigned int B0 = bperm(s0l + 16, w0), B1 = bperm(s0l + 16, w1);
            unsigned int B2 = bperm(s0l + 16, w2), B3 = bperm(s0l + 16, w3);
            const bool hi = (lh >= 2);
            union { unsigned int u[4]; bf16x8 v; } pu;
            pu.u[0] = hi ? A2 : A0;
            pu.u[1] = hi ? A3 : A1;
            pu.u[2] = hi ? B2 : B0;
            pu.u[3] = hi ? B3 : B1;
            const bf16x8 pf = pu.v;
            __builtin_amdgcn_s_setprio(1);
#pragma unroll
            for (int d = 0; d < 8; ++d) {
                const int row = d * 16 + l16;
                const int cv = lh ^ ((row >> 1) & 3);
                bf16x8 vf = *(const bf16x8*)&Vs[cur][row * 32 + cv * 8];
                o[d] = mfma16(vf, pf, o[d]);
            }
            __builtin_amdgcn_s_setprio(0);
        }
        __builtin_amdgcn_s_barrier();          // buf[cur] reads done before overwrite
        cur ^= 1;
    }

    if (ks == 1) {
        const float inv = 1.0f / lsum;
        __bf16* op = Ob + (size_t)(b*SEQ + qw0 + l16) * DIM + h*HDIM;
#pragma unroll
        for (int d = 0; d < 8; ++d) {
            bf16x4 pk;
#pragma unroll
            for (int r = 0; r < 4; ++r) pk[r] = (__bf16)(o[d][r] * inv);
            *(bf16x4*)(op + d*16 + lh*4) = pk;
        }
    } else {
        const int pid = (bh * 32 + tile) * ks + c;
        const int lq  = wv * 16 + l16;
        __bf16* pop = po + ((size_t)pid * 64 + lq) * HDIM;
#pragma unroll
        for (int d = 0; d < 8; ++d) {
            bf16x4 pk;
#pragma unroll
            for (int r = 0; r < 4; ++r) pk[r] = (__bf16)o[d][r];
            *(bf16x4*)(pop + d*16 + lh*4) = pk;
        }
        if (lh == 0) {
            pm[(size_t)pid * 64 + lq] = mx;
            pl[(size_t)pid * 64 + lq] = lsum;
        }
    }
}

// ---------------- merge split-K partials ----------------
__global__ __launch_bounds__(256) void merge_kernel(const __bf16* __restrict__ po,
    const float* __restrict__ pm, const float* __restrict__ pl,
    __bf16* __restrict__ Ob, int ks) {
    const int id = blockIdx.x;             // bh*32 + tile
    const int bh = id >> 5, tile = id & 31;
    const int b = bh / HEADS, h = bh - b * HEADS;
    const int lq = threadIdx.x >> 2;       // 0..63
    const int d0 = (threadIdx.x & 3) * 32;
    const int pb = id * ks;
    float M = -INFINITY;
    for (int cc = 0; cc < ks; ++cc) M = fmaxf(M, pm[(size_t)(pb + cc) * 64 + lq]);
    float L = 0.f, w[2] = {0.f, 0.f};
    for (int cc = 0; cc < ks; ++cc) {
        w[cc] = exp2f(pm[(size_t)(pb + cc) * 64 + lq] - M);
        L += w[cc] * pl[(size_t)(pb + cc) * 64 + lq];
    }
    const float invL = 1.0f / L;
    __bf16* op = Ob + (size_t)(b*SEQ + tile*64 + lq) * DIM + h*HDIM;
#pragma unroll
    for (int d = 0; d < 32; d += 8) {
        float acc[8] = {};
        for (int cc = 0; cc < ks; ++cc) {
            bf16x8 v = *(const bf16x8*)&po[((size_t)(pb + cc) * 64 + lq) * HDIM + d0 + d];
            const float wc = w[cc];
#pragma unroll
            for (int e = 0; e < 8; ++e) acc[e] += wc * (float)v[e];
        }
        bf16x8 ov;
#pragma unroll
        for (int e = 0; e < 8; ++e) ov[e] = (__bf16)(acc[e] * invL);
        *(bf16x8*)(op + d0 + d) = ov;
    }
}

// ---------------- launch ----------------
extern "C" void kernel_launch(void* const* d_in, const int* in_sizes, int n_in,
                              void* d_out, int out_size, void* d_ws, size_t ws_size,
                              hipStream_t stream) {
    const float* x  = (const float*)d_in[0];
    const float* Wq = (const float*)d_in[1];
    const float* bq = (const float*)d_in[2];
    const float* Wk = (const float*)d_in[3];
    const float* bk = (const float*)d_in[4];
    const float* Wv = (const float*)d_in[5];
    const float* bv = (const float*)d_in[6];
    const float* Wo = (const float*)d_in[7];
    const float* bo = (const float*)d_in[8];

    char* p = (char*)d_ws;
    const size_t SZ_X = (size_t)MTOT * DIM * 2;        // 12.6 MB
    const size_t SZ_W = (size_t)DIM * DIM * 2;         // 1.18 MB
    __bf16* xb   = (__bf16*)p; p += SZ_X;
    __bf16* Wcat = (__bf16*)p; p += 3 * SZ_W;          // [2304][768]
    __bf16* Wto  = (__bf16*)p; p += SZ_W;
    __bf16* Qb   = (__bf16*)p; p += SZ_X;
    __bf16* Kb   = (__bf16*)p; p += SZ_X;
    __bf16* Vt   = (__bf16*)p; p += SZ_X;
    __bf16* Ob   = (__bf16*)p; p += SZ_X;

    const size_t base = (size_t)(p - (char*)d_ws);
    const size_t SZ_PO = (size_t)24 * 32 * 2 * 64 * HDIM * 2;  // 25.2 MB (ks=2)
    const size_t SZ_PM = (size_t)24 * 32 * 2 * 64 * 4;         // 0.39 MB
    const int ks = (ws_size >= base + SZ_PO + 2 * SZ_PM) ? 2 : 1;
    __bf16* po = (__bf16*)p;            p += SZ_PO;
    float*  pmv = (float*)p;            p += SZ_PM;
    float*  plv = (float*)p;

    cast_x_kernel<<<(MTOT * DIM) / 1024, 256, 0, stream>>>(x, xb);
    transpose_w_kernel<<<dim3(DIM/32, DIM/32, 4), 256, 0, stream>>>(
        Wq, Wk, Wv, Wo,
        Wcat, Wcat + (size_t)DIM*DIM, Wcat + (size_t)2*DIM*DIM, Wto);

    gemm_qkv<<<(MTOT/128) * (2304/128), 256, 0, stream>>>(xb, Wcat, bq, bk, bv, Qb, Kb, Vt);

    attn_kernel<<<768 * ks, 256, 0, stream>>>(Qb, Kb, Vt, po, pmv, plv, Ob, ks);
    if (ks == 2)
        merge_kernel<<<24 * 32, 256, 0, stream>>>(po, pmv, plv, Ob, ks);

    gemm_out<<<(MTOT/128) * (DIM/128), 256, 0, stream>>>(Ob, Wto, bo, (float*)d_out);
}

// Round 12
// 172.538 us; speedup vs baseline: 1.2478x; 1.0394x over previous
//
#include <hip/hip_runtime.h>
#include <math.h>

#define HEADS 6
#define SEQ   2048
#define DIM   768
#define HDIM  128
#define BATCH 4
#define MTOT  (BATCH*SEQ)   // 8192
#define NKV   (SEQ/32)      // 64

typedef float  f32x4   __attribute__((ext_vector_type(4)));
typedef __bf16 bf16x8  __attribute__((ext_vector_type(8)));
typedef __bf16 bf16x4  __attribute__((ext_vector_type(4)));
typedef float  f32x4v  __attribute__((ext_vector_type(4)));

typedef __attribute__((address_space(3))) void lds_v;
typedef __attribute__((address_space(1))) void gbl_v;

__device__ __forceinline__ f32x4 mfma16(bf16x8 a, bf16x8 b, f32x4 c) {
    return __builtin_amdgcn_mfma_f32_16x16x32_bf16(a, b, c, 0, 0, 0);
}
__device__ __forceinline__ unsigned int bperm(int srclane, unsigned int v) {
    return (unsigned int)__builtin_amdgcn_ds_bpermute(srclane << 2, (int)v);
}
__device__ __forceinline__ unsigned int pack2(float lo, float hi) {
    union { __bf16 b; unsigned short u; } a, c;
    a.b = (__bf16)lo; c.b = (__bf16)hi;
    return ((unsigned int)c.u << 16) | (unsigned int)a.u;
}

// ------- fused prepass: cast x (f32->bf16) + transpose 4 weights -> bf16 -------
// blocks [0, 6144): cast 1024 elems each; blocks [6144, 8448): transpose tiles.
__global__ __launch_bounds__(256) void prep_kernel(
    const float* __restrict__ x, __bf16* __restrict__ xb,
    const float* __restrict__ W0, const float* __restrict__ W1,
    const float* __restrict__ W2, const float* __restrict__ W3,
    __bf16* __restrict__ T0, __bf16* __restrict__ T1,
    __bf16* __restrict__ T2, __bf16* __restrict__ T3) {
    __shared__ float tile[32][33];
    if (blockIdx.x < 6144) {
        int i = (blockIdx.x * 256 + threadIdx.x) * 4;
        f32x4v v = *(const f32x4v*)(x + i);
        bf16x4 o;
        o[0] = (__bf16)v[0]; o[1] = (__bf16)v[1];
        o[2] = (__bf16)v[2]; o[3] = (__bf16)v[3];
        *(bf16x4*)(xb + i) = o;
        return;
    }
    const int bid = blockIdx.x - 6144;          // 0..2303
    const int z = bid / 576, r = bid % 576;
    const int bx = r % 24, by = r / 24;
    const float* W; __bf16* T;
    if      (z == 0) { W = W0; T = T0; }
    else if (z == 1) { W = W1; T = T1; }
    else if (z == 2) { W = W2; T = T2; }
    else             { W = W3; T = T3; }
    int n0 = bx * 32, k0 = by * 32;
    int tx = threadIdx.x & 31, ty = threadIdx.x >> 5;
#pragma unroll
    for (int i = 0; i < 4; ++i)
        tile[ty + i*8][tx] = W[(size_t)(k0 + ty + i*8) * DIM + n0 + tx];
    __syncthreads();
#pragma unroll
    for (int i = 0; i < 4; ++i)
        T[(size_t)(n0 + ty + i*8) * DIM + k0 + tx] = (__bf16)tile[tx][ty + i*8];
}

// ============ GEMM core: triple-buffered LDS, 2-ahead prefetch, vmcnt(4) ============
#define GEMM_PIPE(A_PTR, B_PTR, NKSTEP)                                           \
    __shared__ __align__(16) __bf16 As[3][128 * 32];                              \
    __shared__ __align__(16) __bf16 Bs[3][128 * 32];                              \
    const int tid  = threadIdx.x;                                                 \
    const int wave = tid >> 6, lane = tid & 63;                                   \
    const int l16  = lane & 15, lh = lane >> 4;                                   \
    const int wr = wave >> 1, wc = wave & 1;                                      \
    f32x4 acc[4][4] = {};                                                         \
    auto stage = [&](int buf, int step) {                                         \
        const int k0 = step * 32;                                                 \
        _Pragma("unroll")                                                         \
        for (int ci = 0; ci < 4; ++ci) {                                          \
            int c = wave * 4 + ci;                                                \
            int t = c & 7;                                                        \
            int e = (t * 64 + lane) * 8;                                          \
            int r = e >> 5, kk = e & 31;                                          \
            const __bf16* gp = (c < 8) ? ((A_PTR) + (size_t)(m0 + r) * DIM + k0 + kk) \
                                       : ((B_PTR) + (size_t)(n0 + r) * DIM + k0 + kk); \
            __bf16* lp = (c < 8 ? As[buf] : Bs[buf]) + t * 512;                   \
            __builtin_amdgcn_global_load_lds((const gbl_v*)gp, (lds_v*)lp, 16, 0, 0); \
        }                                                                         \
    };                                                                            \
    stage(0, 0); stage(1, 1);                                                     \
    asm volatile("s_waitcnt vmcnt(4)" ::: "memory");                              \
    __builtin_amdgcn_s_barrier();                                                 \
    for (int t = 0; t < (NKSTEP); ++t) {                                          \
        const int cur = t % 3;                                                    \
        if (t + 2 < (NKSTEP)) stage((t + 2) % 3, t + 2);                          \
        bf16x8 af[4], bfr[4];                                                     \
        _Pragma("unroll")                                                         \
        for (int i = 0; i < 4; ++i)                                               \
            af[i] = *(const bf16x8*)&As[cur][(wr*64 + i*16 + l16) * 32 + lh*8];   \
        _Pragma("unroll")                                                         \
        for (int j = 0; j < 4; ++j)                                               \
            bfr[j] = *(const bf16x8*)&Bs[cur][(wc*64 + j*16 + l16) * 32 + lh*8];  \
        __builtin_amdgcn_s_setprio(1);                                            \
        _Pragma("unroll")                                                         \
        for (int i = 0; i < 4; ++i)                                               \
            _Pragma("unroll")                                                     \
            for (int j = 0; j < 4; ++j)                                           \
                acc[i][j] = mfma16(af[i], bfr[j], acc[i][j]);                     \
        __builtin_amdgcn_s_setprio(0);                                            \
        if (t + 2 < (NKSTEP))      asm volatile("s_waitcnt vmcnt(4)" ::: "memory"); \
        else if (t + 1 < (NKSTEP)) asm volatile("s_waitcnt vmcnt(0)" ::: "memory"); \
        __builtin_amdgcn_s_barrier();                                             \
    }

// ---------------- fused QKV GEMM: [8192,768] @ Wcat[2304,768]^T ----------------
// XCD-bijective swizzle: each XCD owns a contiguous 8-wide bm band (A-panel
// 1.5MB + W 3.5MB ~ L2-fit per XCD).
__global__ __launch_bounds__(256) void gemm_qkv(const __bf16* __restrict__ A,
                                                const __bf16* __restrict__ Wcat,
                                                const float* __restrict__ bq,
                                                const float* __restrict__ bk,
                                                const float* __restrict__ bv,
                                                __bf16* __restrict__ Qb,
                                                __bf16* __restrict__ Kb,
                                                __bf16* __restrict__ Vt) {
    constexpr int NWG = (MTOT/128) * (2304/128);    // 1152, %8==0
    const int swz = (blockIdx.x & 7) * (NWG >> 3) + (blockIdx.x >> 3);
    const int bn = swz % (2304 / 128), bm = swz / (2304 / 128);
    const int m0 = bm * 128, n0 = bn * 128;
    GEMM_PIPE(A, Wcat, 24)

    const int sel = n0 / DIM;                 // 0=Q 1=K 2=V (block-uniform)
    const float* bias = sel == 0 ? bq : (sel == 1 ? bk : bv);
#pragma unroll
    for (int i = 0; i < 4; ++i) {
        int row = m0 + wr*64 + i*16 + lh*4;
#pragma unroll
        for (int j = 0; j < 4; ++j) {
            int col  = n0 + wc*64 + j*16 + l16;
            int lcol = col - sel * DIM;
            float bvv = bias[lcol];
            if (sel < 2) {
                __bf16* o = (sel == 0) ? Qb : Kb;
#pragma unroll
                for (int r = 0; r < 4; ++r)
                    o[(size_t)(row + r) * DIM + lcol] = (__bf16)(acc[i][j][r] + bvv);
            } else {
                int bb = row >> 11, ll = row & (SEQ - 1);
                int hh = lcol >> 7, dd = lcol & (HDIM - 1);
                bf16x4 pk;
#pragma unroll
                for (int r = 0; r < 4; ++r) pk[r] = (__bf16)(acc[i][j][r] + bvv);
                *(bf16x4*)&Vt[((size_t)((bb*HEADS + hh) * HDIM + dd)) * SEQ + ll] = pk;
            }
        }
    }
}

// ---------------- out-proj GEMM: [8192,768] @ Wto[768,768]^T -> f32 ----------------
__global__ __launch_bounds__(256) void gemm_out(const __bf16* __restrict__ A,
                                                const __bf16* __restrict__ Bt,
                                                const float* __restrict__ bias,
                                                float* __restrict__ outp) {
    constexpr int NWG = (MTOT/128) * (DIM/128);     // 384, %8==0
    const int swz = (blockIdx.x & 7) * (NWG >> 3) + (blockIdx.x >> 3);
    const int bn = swz % (DIM / 128), bm = swz / (DIM / 128);
    const int m0 = bm * 128, n0 = bn * 128;
    GEMM_PIPE(A, Bt, 24)

#pragma unroll
    for (int i = 0; i < 4; ++i) {
        int row = m0 + wr*64 + i*16 + lh*4;
#pragma unroll
        for (int j = 0; j < 4; ++j) {
            int col = n0 + wc*64 + j*16 + l16;
            float bv = bias[col];
#pragma unroll
            for (int r = 0; r < 4; ++r)
                outp[(size_t)(row + r) * DIM + col] = acc[i][j][r] + bv;
        }
    }
}

// ---------------- flash attention (r3-verbatim, measured 94 us) ----------------
// Block = 4 waves x 16 q-rows = 64 q-rows. Chunk c handles k-blocks kb ≡ c (mod ks).
// K/V double-buffered in LDS via global_load_lds with XOR-swizzled source.
// Swapped QK^T (s = mfma(K,Q)); softmax in-register; P via ds_bpermute;
// PV computes O^T (o = mfma(V^T, P)). Causal mask: key <= q+1 (tril k=1).
__global__ __launch_bounds__(256, 3) void attn_kernel(
    const __bf16* __restrict__ Q, const __bf16* __restrict__ K,
    const __bf16* __restrict__ Vt,
    __bf16* __restrict__ po, float* __restrict__ pm, float* __restrict__ pl,
    __bf16* __restrict__ Ob, int ks) {
    __shared__ __align__(16) __bf16 Ks[2][32 * 128];
    __shared__ __align__(16) __bf16 Vs[2][128 * 32];
    const int lane = threadIdx.x & 63, wv = threadIdx.x >> 6;
    const int l16 = lane & 15, lh = lane >> 4;
    // grid: 8 xcd x 3 bh_l x 32 tl x ks  -> bh pinned to XCD (blockIdx % 8)
    const int id  = blockIdx.x;
    const int xcd = id & 7;
    const int idx = id >> 3;
    const int bh_l = idx % 3, rem = idx / 3;
    const int c = rem % ks, tl = rem / ks;
    const int tile = (tl & 1) ? (31 - (tl >> 1)) : (tl >> 1);   // heavy/light mix
    const int bh = xcd + 8 * bh_l;
    const int b = bh / HEADS, h = bh - b * HEADS;
    const int qw0 = tile * 64 + wv * 16;
    const float qs = 0.12751674770951932f;  // 1/sqrt(128) * log2(e)

    bf16x8 qf[4];
    {
        const __bf16* qp = Q + (size_t)(b*SEQ + qw0 + l16) * DIM + h*HDIM + lh*8;
#pragma unroll
        for (int kk = 0; kk < 4; ++kk) {
            bf16x8 v = *(const bf16x8*)(qp + kk*32);
            bf16x8 sv;
#pragma unroll
            for (int e = 0; e < 8; ++e) sv[e] = (__bf16)((float)v[e] * qs);
            qf[kk] = sv;
        }
    }

    const __bf16* kgb = K  + (size_t)(b*SEQ) * DIM + h*HDIM;
    const __bf16* vgb = Vt + (size_t)bh * HDIM * SEQ;

    // stage one k-block (K: 32x128 swizzled, V: 128x32 swizzled) -> 16 lds-loads/4 waves
    auto stage = [&](int buf, int kb) {
        const int kbase = kb * 32;
#pragma unroll
        for (int s = 0; s < 4; ++s) {
            const int j = wv * 4 + s;          // wave-uniform
            if (j < 8) {
                const int row = j * 4 + (lane >> 4);
                const int c16 = (lane & 15) ^ (row & 7);      // pre-swizzled source
                const __bf16* gp = kgb + (size_t)(kbase + row) * DIM + c16 * 8;
                __builtin_amdgcn_global_load_lds((const gbl_v*)gp,
                    (lds_v*)&Ks[buf][j * 512], 16, 0, 0);
            } else {
                const int jj = j - 8;
                const int row = jj * 16 + (lane >> 2);
                const int c16 = (lane & 3) ^ ((row >> 1) & 3);
                const __bf16* gp = vgb + (size_t)row * SEQ + kbase + c16 * 8;
                __builtin_amdgcn_global_load_lds((const gbl_v*)gp,
                    (lds_v*)&Vs[buf][jj * 512], 16, 0, 0);
            }
        }
    };

    f32x4 o[8] = {};
    float mx = -INFINITY, lsum = 0.f;
    const int nkb = min(2 * tile + 3, NKV);
    const int cnt = (nkb - c + ks - 1) / ks;

    stage(0, c);
    asm volatile("s_waitcnt vmcnt(0)" ::: "memory");
    __builtin_amdgcn_s_barrier();

    int cur = 0;
    for (int i = 0; i < cnt; ++i) {
        const int kb = c + i * ks;
        const int kbase = kb * 32;
        const bool more = (i + 1 < cnt);       // block-uniform
        if (more) {
            stage(cur ^ 1, kb + ks);
            asm volatile("s_waitcnt vmcnt(4)" ::: "memory");  // prev stage done, next in flight
        } else {
            asm volatile("s_waitcnt vmcnt(0)" ::: "memory");
        }
        __builtin_amdgcn_s_barrier();          // buf[cur] valid for all waves

        if (kbase <= qw0 + 16) {               // wave-uniform activity test
            bf16x8 kfA[4], kfB[4];
#pragma unroll
            for (int kk = 0; kk < 4; ++kk) {
                const int ca = (kk*4 + lh) ^ (l16 & 7);
                kfA[kk] = *(const bf16x8*)&Ks[cur][l16 * 128 + ca * 8];
                const int rb = 16 + l16;
                const int cb = (kk*4 + lh) ^ (rb & 7);
                kfB[kk] = *(const bf16x8*)&Ks[cur][rb * 128 + cb * 8];
            }
            f32x4 sA = {}, sB = {};
            __builtin_amdgcn_s_setprio(1);
#pragma unroll
            for (int kk = 0; kk < 4; ++kk) {
                sA = mfma16(kfA[kk], qf[kk], sA);
                sB = mfma16(kfB[kk], qf[kk], sB);
            }
            __builtin_amdgcn_s_setprio(0);
            const int q = qw0 + l16;
            float p[8];
#pragma unroll
            for (int r = 0; r < 4; ++r) { p[r] = sA[r]; p[r+4] = sB[r]; }
            if (kbase + 30 > qw0) {            // diagonal: apply causal mask
#pragma unroll
                for (int r = 0; r < 4; ++r) {
                    const int key = kbase + lh*4 + r;
                    if (key      > q + 1) p[r]   = -INFINITY;
                    if (key + 16 > q + 1) p[r+4] = -INFINITY;
                }
            }
            float m0 = p[0];
#pragma unroll
            for (int t2 = 1; t2 < 8; ++t2) m0 = fmaxf(m0, p[t2]);
            m0 = fmaxf(m0, __shfl_xor(m0, 16));
            m0 = fmaxf(m0, __shfl_xor(m0, 32));
            const float mnew = fmaxf(mx, m0);
            const bool grow = m0 > mx;
            const float mref = (mnew == -INFINITY) ? 0.f : mnew;  // NaN guard (split-K)
#pragma unroll
            for (int t2 = 0; t2 < 8; ++t2) p[t2] = exp2f(p[t2] - mref);
            float rs = 0.f;
#pragma unroll
            for (int t2 = 0; t2 < 8; ++t2) rs += p[t2];
            rs += __shfl_xor(rs, 16);
            rs += __shfl_xor(rs, 32);
            if (__any(grow)) {
                const float resc = (mx < mnew) ? exp2f(mx - mnew) : 1.0f;  // NaN guard
                lsum = lsum * resc + rs;
                mx = mnew;
#pragma unroll
                for (int d = 0; d < 8; ++d)
#pragma unroll
                    for (int r = 0; r < 4; ++r) o[d][r] *= resc;
            } else {
                lsum += rs;
            }
            unsigned int w0 = pack2(p[0], p[1]);
            unsigned int w1 = pack2(p[2], p[3]);
            unsigned int w2 = pack2(p[4], p[5]);
            unsigned int w3 = pack2(p[6], p[7]);
            const int s0l = l16 + ((lh & 1) << 5);
            unsigned int A0 = bperm(s0l,      w0), A1 = bperm(s0l,      w1);
            unsigned int A2 = bperm(s0l,      w2), A3 = bperm(s0l,      w3);
            unsigned int B0 = bperm(s0l + 16, w0), B1 = bperm(s0l + 16, w1);
            unsigned int B2 = bperm(s0l + 16, w2), B3 = bperm(s0l + 16, w3);
            const bool hi = (lh >= 2);
            union { unsigned int u[4]; bf16x8 v; } pu;
            pu.u[0] = hi ? A2 : A0;
            pu.u[1] = hi ? A3 : A1;
            pu.u[2] = hi ? B2 : B0;
            pu.u[3] = hi ? B3 : B1;
            const bf16x8 pf = pu.v;
            __builtin_amdgcn_s_setprio(1);
#pragma unroll
            for (int d = 0; d < 8; ++d) {
                const int row = d * 16 + l16;
                const int cv = lh ^ ((row >> 1) & 3);
                bf16x8 vf = *(const bf16x8*)&Vs[cur][row * 32 + cv * 8];
                o[d] = mfma16(vf, pf, o[d]);
            }
            __builtin_amdgcn_s_setprio(0);
        }
        __builtin_amdgcn_s_barrier();          // buf[cur] reads done before overwrite
        cur ^= 1;
    }

    if (ks == 1) {
        const float inv = 1.0f / lsum;
        __bf16* op = Ob + (size_t)(b*SEQ + qw0 + l16) * DIM + h*HDIM;
#pragma unroll
        for (int d = 0; d < 8; ++d) {
            bf16x4 pk;
#pragma unroll
            for (int r = 0; r < 4; ++r) pk[r] = (__bf16)(o[d][r] * inv);
            *(bf16x4*)(op + d*16 + lh*4) = pk;
        }
    } else {
        const int pid = (bh * 32 + tile) * ks + c;
        const int lq  = wv * 16 + l16;
        __bf16* pop = po + ((size_t)pid * 64 + lq) * HDIM;
#pragma unroll
        for (int d = 0; d < 8; ++d) {
            bf16x4 pk;
#pragma unroll
            for (int r = 0; r < 4; ++r) pk[r] = (__bf16)o[d][r];
            *(bf16x4*)(pop + d*16 + lh*4) = pk;
        }
        if (lh == 0) {
            pm[(size_t)pid * 64 + lq] = mx;
            pl[(size_t)pid * 64 + lq] = lsum;
        }
    }
}

// ---------------- merge split-K partials ----------------
__global__ __launch_bounds__(256) void merge_kernel(const __bf16* __restrict__ po,
    const float* __restrict__ pm, const float* __restrict__ pl,
    __bf16* __restrict__ Ob, int ks) {
    const int id = blockIdx.x;             // bh*32 + tile
    const int bh = id >> 5, tile = id & 31;
    const int b = bh / HEADS, h = bh - b * HEADS;
    const int lq = threadIdx.x >> 2;       // 0..63
    const int d0 = (threadIdx.x & 3) * 32;
    const int pb = id * ks;
    float M = -INFINITY;
    for (int cc = 0; cc < ks; ++cc) M = fmaxf(M, pm[(size_t)(pb + cc) * 64 + lq]);
    float L = 0.f, w[2] = {0.f, 0.f};
    for (int cc = 0; cc < ks; ++cc) {
        w[cc] = exp2f(pm[(size_t)(pb + cc) * 64 + lq] - M);
        L += w[cc] * pl[(size_t)(pb + cc) * 64 + lq];
    }
    const float invL = 1.0f / L;
    __bf16* op = Ob + (size_t)(b*SEQ + tile*64 + lq) * DIM + h*HDIM;
#pragma unroll
    for (int d = 0; d < 32; d += 8) {
        float acc[8] = {};
        for (int cc = 0; cc < ks; ++cc) {
            bf16x8 v = *(const bf16x8*)&po[((size_t)(pb + cc) * 64 + lq) * HDIM + d0 + d];
            const float wc = w[cc];
#pragma unroll
            for (int e = 0; e < 8; ++e) acc[e] += wc * (float)v[e];
        }
        bf16x8 ov;
#pragma unroll
        for (int e = 0; e < 8; ++e) ov[e] = (__bf16)(acc[e] * invL);
        *(bf16x8*)(op + d0 + d) = ov;
    }
}

// ---------------- launch ----------------
extern "C" void kernel_launch(void* const* d_in, const int* in_sizes, int n_in,
                              void* d_out, int out_size, void* d_ws, size_t ws_size,
                              hipStream_t stream) {
    const float* x  = (const float*)d_in[0];
    const float* Wq = (const float*)d_in[1];
    const float* bq = (const float*)d_in[2];
    const float* Wk = (const float*)d_in[3];
    const float* bk = (const float*)d_in[4];
    const float* Wv = (const float*)d_in[5];
    const float* bv = (const float*)d_in[6];
    const float* Wo = (const float*)d_in[7];
    const float* bo = (const float*)d_in[8];

    char* p = (char*)d_ws;
    const size_t SZ_X = (size_t)MTOT * DIM * 2;        // 12.6 MB
    const size_t SZ_W = (size_t)DIM * DIM * 2;         // 1.18 MB
    __bf16* xb   = (__bf16*)p; p += SZ_X;
    __bf16* Wcat = (__bf16*)p; p += 3 * SZ_W;          // [2304][768]
    __bf16* Wto  = (__bf16*)p; p += SZ_W;
    __bf16* Qb   = (__bf16*)p; p += SZ_X;
    __bf16* Kb   = (__bf16*)p; p += SZ_X;
    __bf16* Vt   = (__bf16*)p; p += SZ_X;
    __bf16* Ob   = (__bf16*)p; p += SZ_X;

    const size_t base = (size_t)(p - (char*)d_ws);
    const size_t SZ_PO = (size_t)24 * 32 * 2 * 64 * HDIM * 2;  // 25.2 MB (ks=2)
    const size_t SZ_PM = (size_t)24 * 32 * 2 * 64 * 4;         // 0.39 MB
    const int ks = (ws_size >= base + SZ_PO + 2 * SZ_PM) ? 2 : 1;
    __bf16* po = (__bf16*)p;            p += SZ_PO;
    float*  pmv = (float*)p;            p += SZ_PM;
    float*  plv = (float*)p;

    prep_kernel<<<6144 + 2304, 256, 0, stream>>>(
        x, xb, Wq, Wk, Wv, Wo,
        Wcat, Wcat + (size_t)DIM*DIM, Wcat + (size_t)2*DIM*DIM, Wto);

    gemm_qkv<<<(MTOT/128) * (2304/128), 256, 0, stream>>>(xb, Wcat, bq, bk, bv, Qb, Kb, Vt);

    attn_kernel<<<768 * ks, 256, 0, stream>>>(Qb, Kb, Vt, po, pmv, plv, Ob, ks);
    if (ks == 2)
        merge_kernel<<<24 * 32, 256, 0, stream>>>(po, pmv, plv, Ob, ks);

    gemm_out<<<(MTOT/128) * (DIM/128), 256, 0, stream>>>(Ob, Wto, bo, (float*)d_out);
}

// Round 13
// 168.405 us; speedup vs baseline: 1.2784x; 1.0245x over previous
//
#include <hip/hip_runtime.h>
#include <math.h>

#define HEADS 6
#define SEQ   2048
#define DIM   768
#define HDIM  128
#define BATCH 4
#define MTOT  (BATCH*SEQ)   // 8192
#define NKV   (SEQ/32)      // 64
#define NCHUNK_TOT 83       // sum over 32 tiles of ceil(min(2t+3,64)/16)

typedef float  f32x4   __attribute__((ext_vector_type(4)));
typedef __bf16 bf16x8  __attribute__((ext_vector_type(8)));
typedef __bf16 bf16x4  __attribute__((ext_vector_type(4)));
typedef float  f32x4v  __attribute__((ext_vector_type(4)));

typedef __attribute__((address_space(3))) void lds_v;
typedef __attribute__((address_space(1))) void gbl_v;

__device__ __forceinline__ f32x4 mfma16(bf16x8 a, bf16x8 b, f32x4 c) {
    return __builtin_amdgcn_mfma_f32_16x16x32_bf16(a, b, c, 0, 0, 0);
}
__device__ __forceinline__ unsigned int bperm(int srclane, unsigned int v) {
    return (unsigned int)__builtin_amdgcn_ds_bpermute(srclane << 2, (int)v);
}
__device__ __forceinline__ unsigned int pack2(float lo, float hi) {
    union { __bf16 b; unsigned short u; } a, c;
    a.b = (__bf16)lo; c.b = (__bf16)hi;
    return ((unsigned int)c.u << 16) | (unsigned int)a.u;
}

// ------- fused prepass: cast x (f32->bf16) + transpose 4 weights -> bf16 -------
__global__ __launch_bounds__(256) void prep_kernel(
    const float* __restrict__ x, __bf16* __restrict__ xb,
    const float* __restrict__ W0, const float* __restrict__ W1,
    const float* __restrict__ W2, const float* __restrict__ W3,
    __bf16* __restrict__ T0, __bf16* __restrict__ T1,
    __bf16* __restrict__ T2, __bf16* __restrict__ T3) {
    __shared__ float tile[32][33];
    if (blockIdx.x < 6144) {
        int i = (blockIdx.x * 256 + threadIdx.x) * 4;
        f32x4v v = *(const f32x4v*)(x + i);
        bf16x4 o;
        o[0] = (__bf16)v[0]; o[1] = (__bf16)v[1];
        o[2] = (__bf16)v[2]; o[3] = (__bf16)v[3];
        *(bf16x4*)(xb + i) = o;
        return;
    }
    const int bid = blockIdx.x - 6144;          // 0..2303
    const int z = bid / 576, r = bid % 576;
    const int bx = r % 24, by = r / 24;
    const float* W; __bf16* T;
    if      (z == 0) { W = W0; T = T0; }
    else if (z == 1) { W = W1; T = T1; }
    else if (z == 2) { W = W2; T = T2; }
    else             { W = W3; T = T3; }
    int n0 = bx * 32, k0 = by * 32;
    int tx = threadIdx.x & 31, ty = threadIdx.x >> 5;
#pragma unroll
    for (int i = 0; i < 4; ++i)
        tile[ty + i*8][tx] = W[(size_t)(k0 + ty + i*8) * DIM + n0 + tx];
    __syncthreads();
#pragma unroll
    for (int i = 0; i < 4; ++i)
        T[(size_t)(n0 + ty + i*8) * DIM + k0 + tx] = (__bf16)tile[tx][ty + i*8];
}

// ============ GEMM core: triple-buffered LDS, 2-ahead prefetch, vmcnt(4) ============
#define GEMM_PIPE(A_PTR, B_PTR, NKSTEP)                                           \
    __shared__ __align__(16) __bf16 As[3][128 * 32];                              \
    __shared__ __align__(16) __bf16 Bs[3][128 * 32];                              \
    const int tid  = threadIdx.x;                                                 \
    const int wave = tid >> 6, lane = tid & 63;                                   \
    const int l16  = lane & 15, lh = lane >> 4;                                   \
    const int wr = wave >> 1, wc = wave & 1;                                      \
    f32x4 acc[4][4] = {};                                                         \
    auto stage = [&](int buf, int step) {                                         \
        const int k0 = step * 32;                                                 \
        _Pragma("unroll")                                                         \
        for (int ci = 0; ci < 4; ++ci) {                                          \
            int c = wave * 4 + ci;                                                \
            int t = c & 7;                                                        \
            int e = (t * 64 + lane) * 8;                                          \
            int r = e >> 5, kk = e & 31;                                          \
            const __bf16* gp = (c < 8) ? ((A_PTR) + (size_t)(m0 + r) * DIM + k0 + kk) \
                                       : ((B_PTR) + (size_t)(n0 + r) * DIM + k0 + kk); \
            __bf16* lp = (c < 8 ? As[buf] : Bs[buf]) + t * 512;                   \
            __builtin_amdgcn_global_load_lds((const gbl_v*)gp, (lds_v*)lp, 16, 0, 0); \
        }                                                                         \
    };                                                                            \
    stage(0, 0); stage(1, 1);                                                     \
    asm volatile("s_waitcnt vmcnt(4)" ::: "memory");                              \
    __builtin_amdgcn_s_barrier();                                                 \
    for (int t = 0; t < (NKSTEP); ++t) {                                          \
        const int cur = t % 3;                                                    \
        if (t + 2 < (NKSTEP)) stage((t + 2) % 3, t + 2);                          \
        bf16x8 af[4], bfr[4];                                                     \
        _Pragma("unroll")                                                         \
        for (int i = 0; i < 4; ++i)                                               \
            af[i] = *(const bf16x8*)&As[cur][(wr*64 + i*16 + l16) * 32 + lh*8];   \
        _Pragma("unroll")                                                         \
        for (int j = 0; j < 4; ++j)                                               \
            bfr[j] = *(const bf16x8*)&Bs[cur][(wc*64 + j*16 + l16) * 32 + lh*8];  \
        __builtin_amdgcn_s_setprio(1);                                            \
        _Pragma("unroll")                                                         \
        for (int i = 0; i < 4; ++i)                                               \
            _Pragma("unroll")                                                     \
            for (int j = 0; j < 4; ++j)                                           \
                acc[i][j] = mfma16(af[i], bfr[j], acc[i][j]);                     \
        __builtin_amdgcn_s_setprio(0);                                            \
        if (t + 2 < (NKSTEP))      asm volatile("s_waitcnt vmcnt(4)" ::: "memory"); \
        else if (t + 1 < (NKSTEP)) asm volatile("s_waitcnt vmcnt(0)" ::: "memory"); \
        __builtin_amdgcn_s_barrier();                                             \
    }

// ---------------- fused QKV GEMM: [8192,768] @ Wcat[2304,768]^T ----------------
__global__ __launch_bounds__(256) void gemm_qkv(const __bf16* __restrict__ A,
                                                const __bf16* __restrict__ Wcat,
                                                const float* __restrict__ bq,
                                                const float* __restrict__ bk,
                                                const float* __restrict__ bv,
                                                __bf16* __restrict__ Qb,
                                                __bf16* __restrict__ Kb,
                                                __bf16* __restrict__ Vt) {
    constexpr int NWG = (MTOT/128) * (2304/128);    // 1152, %8==0
    const int swz = (blockIdx.x & 7) * (NWG >> 3) + (blockIdx.x >> 3);
    const int bn = swz % (2304 / 128), bm = swz / (2304 / 128);
    const int m0 = bm * 128, n0 = bn * 128;
    GEMM_PIPE(A, Wcat, 24)

    const int sel = n0 / DIM;                 // 0=Q 1=K 2=V (block-uniform)
    const float* bias = sel == 0 ? bq : (sel == 1 ? bk : bv);
#pragma unroll
    for (int i = 0; i < 4; ++i) {
        int row = m0 + wr*64 + i*16 + lh*4;
#pragma unroll
        for (int j = 0; j < 4; ++j) {
            int col  = n0 + wc*64 + j*16 + l16;
            int lcol = col - sel * DIM;
            float bvv = bias[lcol];
            if (sel < 2) {
                __bf16* o = (sel == 0) ? Qb : Kb;
#pragma unroll
                for (int r = 0; r < 4; ++r)
                    o[(size_t)(row + r) * DIM + lcol] = (__bf16)(acc[i][j][r] + bvv);
            } else {
                int bb = row >> 11, ll = row & (SEQ - 1);
                int hh = lcol >> 7, dd = lcol & (HDIM - 1);
                bf16x4 pk;
#pragma unroll
                for (int r = 0; r < 4; ++r) pk[r] = (__bf16)(acc[i][j][r] + bvv);
                *(bf16x4*)&Vt[((size_t)((bb*HEADS + hh) * HDIM + dd)) * SEQ + ll] = pk;
            }
        }
    }
}

// ---------------- out-proj GEMM: [8192,768] @ Wto[768,768]^T -> f32 ----------------
__global__ __launch_bounds__(256) void gemm_out(const __bf16* __restrict__ A,
                                                const __bf16* __restrict__ Bt,
                                                const float* __restrict__ bias,
                                                float* __restrict__ outp) {
    constexpr int NWG = (MTOT/128) * (DIM/128);     // 384, %8==0
    const int swz = (blockIdx.x & 7) * (NWG >> 3) + (blockIdx.x >> 3);
    const int bn = swz % (DIM / 128), bm = swz / (DIM / 128);
    const int m0 = bm * 128, n0 = bn * 128;
    GEMM_PIPE(A, Bt, 24)

#pragma unroll
    for (int i = 0; i < 4; ++i) {
        int row = m0 + wr*64 + i*16 + lh*4;
#pragma unroll
        for (int j = 0; j < 4; ++j) {
            int col = n0 + wc*64 + j*16 + l16;
            float bv = bias[col];
#pragma unroll
            for (int r = 0; r < 4; ++r)
                outp[(size_t)(row + r) * DIM + col] = acc[i][j][r] + bv;
        }
    }
}

// ---------------- flash attention: r3 inner loop + fixed-size chunks (L=16) -------
// Work quantum = (bh, tile, chunk): chunk covers k-blocks [16c, min(16c+16, nkb)).
// nc(tile)=ceil(nkb/16) in 1..4; 83 chunks/bh; grid 8x3x83=1992 near-uniform
// blocks, heavy-first (LPT). Single-chunk tiles write Ob directly; others write
// partials (po/pm/pl) merged by merge_kernel. Inner loop identical to r3 (94us).
__global__ __launch_bounds__(256, 3) void attn_kernel(
    const __bf16* __restrict__ Q, const __bf16* __restrict__ K,
    const __bf16* __restrict__ Vt,
    __bf16* __restrict__ po, float* __restrict__ pm, float* __restrict__ pl,
    __bf16* __restrict__ Ob) {
    __shared__ __align__(16) __bf16 Ks[2][32 * 128];
    __shared__ __align__(16) __bf16 Vs[2][128 * 32];
    const int lane = threadIdx.x & 63, wv = threadIdx.x >> 6;
    const int l16 = lane & 15, lh = lane >> 4;
    // grid: 8 xcd x 3 bh_l x 83 chunks -> bh pinned to XCD
    const int id  = blockIdx.x;
    const int xcd = id & 7;
    const int idx = id >> 3;
    const int bh_l = idx % 3;
    const int ci = (NCHUNK_TOT - 1) - idx / 3;      // LPT: heavy chunks first
    int tile, chunk;
    if      (ci < 7)  { tile = ci;                chunk = 0;          }
    else if (ci < 23) { tile = 7  + (ci-7)/2;     chunk = (ci-7)&1;   }
    else if (ci < 47) { tile = 15 + (ci-23)/3;    chunk = (ci-23)%3;  }
    else              { tile = 23 + (ci-47)/4;    chunk = (ci-47)&3;  }
    const int cstart = ci - chunk;
    const int bh = xcd + 8 * bh_l;
    const int b = bh / HEADS, h = bh - b * HEADS;
    const int qw0 = tile * 64 + wv * 16;
    const int nkb = min(2 * tile + 3, NKV);
    const int nc  = (nkb + 15) >> 4;
    const int lo  = chunk * 16;
    const int cnt = min(lo + 16, nkb) - lo;
    const float qs = 0.12751674770951932f;  // 1/sqrt(128) * log2(e)

    bf16x8 qf[4];
    {
        const __bf16* qp = Q + (size_t)(b*SEQ + qw0 + l16) * DIM + h*HDIM + lh*8;
#pragma unroll
        for (int kk = 0; kk < 4; ++kk) {
            bf16x8 v = *(const bf16x8*)(qp + kk*32);
            bf16x8 sv;
#pragma unroll
            for (int e = 0; e < 8; ++e) sv[e] = (__bf16)((float)v[e] * qs);
            qf[kk] = sv;
        }
    }

    const __bf16* kgb = K  + (size_t)(b*SEQ) * DIM + h*HDIM;
    const __bf16* vgb = Vt + (size_t)bh * HDIM * SEQ;

    auto stage = [&](int buf, int kb) {
        const int kbase = kb * 32;
#pragma unroll
        for (int s = 0; s < 4; ++s) {
            const int j = wv * 4 + s;          // wave-uniform
            if (j < 8) {
                const int row = j * 4 + (lane >> 4);
                const int c16 = (lane & 15) ^ (row & 7);      // pre-swizzled source
                const __bf16* gp = kgb + (size_t)(kbase + row) * DIM + c16 * 8;
                __builtin_amdgcn_global_load_lds((const gbl_v*)gp,
                    (lds_v*)&Ks[buf][j * 512], 16, 0, 0);
            } else {
                const int jj = j - 8;
                const int row = jj * 16 + (lane >> 2);
                const int c16 = (lane & 3) ^ ((row >> 1) & 3);
                const __bf16* gp = vgb + (size_t)row * SEQ + kbase + c16 * 8;
                __builtin_amdgcn_global_load_lds((const gbl_v*)gp,
                    (lds_v*)&Vs[buf][jj * 512], 16, 0, 0);
            }
        }
    };

    f32x4 o[8] = {};
    float mx = -INFINITY, lsum = 0.f;

    stage(0, lo);
    asm volatile("s_waitcnt vmcnt(0)" ::: "memory");
    __builtin_amdgcn_s_barrier();

    int cur = 0;
    for (int i = 0; i < cnt; ++i) {
        const int kb = lo + i;
        const int kbase = kb * 32;
        const bool more = (i + 1 < cnt);       // block-uniform
        if (more) {
            stage(cur ^ 1, kb + 1);
            asm volatile("s_waitcnt vmcnt(4)" ::: "memory");  // prev stage done, next in flight
        } else {
            asm volatile("s_waitcnt vmcnt(0)" ::: "memory");
        }
        __builtin_amdgcn_s_barrier();          // buf[cur] valid for all waves

        if (kbase <= qw0 + 16) {               // wave-uniform activity test
            bf16x8 kfA[4], kfB[4];
#pragma unroll
            for (int kk = 0; kk < 4; ++kk) {
                const int ca = (kk*4 + lh) ^ (l16 & 7);
                kfA[kk] = *(const bf16x8*)&Ks[cur][l16 * 128 + ca * 8];
                const int rb = 16 + l16;
                const int cb = (kk*4 + lh) ^ (rb & 7);
                kfB[kk] = *(const bf16x8*)&Ks[cur][rb * 128 + cb * 8];
            }
            f32x4 sA = {}, sB = {};
            __builtin_amdgcn_s_setprio(1);
#pragma unroll
            for (int kk = 0; kk < 4; ++kk) {
                sA = mfma16(kfA[kk], qf[kk], sA);
                sB = mfma16(kfB[kk], qf[kk], sB);
            }
            __builtin_amdgcn_s_setprio(0);
            const int q = qw0 + l16;
            float p[8];
#pragma unroll
            for (int r = 0; r < 4; ++r) { p[r] = sA[r]; p[r+4] = sB[r]; }
            if (kbase + 30 > qw0) {            // diagonal: apply causal mask
#pragma unroll
                for (int r = 0; r < 4; ++r) {
                    const int key = kbase + lh*4 + r;
                    if (key      > q + 1) p[r]   = -INFINITY;
                    if (key + 16 > q + 1) p[r+4] = -INFINITY;
                }
            }
            float m0 = p[0];
#pragma unroll
            for (int t2 = 1; t2 < 8; ++t2) m0 = fmaxf(m0, p[t2]);
            m0 = fmaxf(m0, __shfl_xor(m0, 16));
            m0 = fmaxf(m0, __shfl_xor(m0, 32));
            const float mnew = fmaxf(mx, m0);
            const bool grow = m0 > mx;
            const float mref = (mnew == -INFINITY) ? 0.f : mnew;  // all-masked guard
#pragma unroll
            for (int t2 = 0; t2 < 8; ++t2) p[t2] = exp2f(p[t2] - mref);
            float rs = 0.f;
#pragma unroll
            for (int t2 = 0; t2 < 8; ++t2) rs += p[t2];
            rs += __shfl_xor(rs, 16);
            rs += __shfl_xor(rs, 32);
            if (__any(grow)) {
                const float resc = (mx < mnew) ? exp2f(mx - mnew) : 1.0f;  // NaN guard
                lsum = lsum * resc + rs;
                mx = mnew;
#pragma unroll
                for (int d = 0; d < 8; ++d)
#pragma unroll
                    for (int r = 0; r < 4; ++r) o[d][r] *= resc;
            } else {
                lsum += rs;
            }
            unsigned int w0 = pack2(p[0], p[1]);
            unsigned int w1 = pack2(p[2], p[3]);
            unsigned int w2 = pack2(p[4], p[5]);
            unsigned int w3 = pack2(p[6], p[7]);
            const int s0l = l16 + ((lh & 1) << 5);
            unsigned int A0 = bperm(s0l,      w0), A1 = bperm(s0l,      w1);
            unsigned int A2 = bperm(s0l,      w2), A3 = bperm(s0l,      w3);
            unsigned int B0 = bperm(s0l + 16, w0), B1 = bperm(s0l + 16, w1);
            unsigned int B2 = bperm(s0l + 16, w2), B3 = bperm(s0l + 16, w3);
            const bool hi = (lh >= 2);
            union { unsigned int u[4]; bf16x8 v; } pu;
            pu.u[0] = hi ? A2 : A0;
            pu.u[1] = hi ? A3 : A1;
            pu.u[2] = hi ? B2 : B0;
            pu.u[3] = hi ? B3 : B1;
            const bf16x8 pf = pu.v;
            __builtin_amdgcn_s_setprio(1);
#pragma unroll
            for (int d = 0; d < 8; ++d) {
                const int row = d * 16 + l16;
                const int cv = lh ^ ((row >> 1) & 3);
                bf16x8 vf = *(const bf16x8*)&Vs[cur][row * 32 + cv * 8];
                o[d] = mfma16(vf, pf, o[d]);
            }
            __builtin_amdgcn_s_setprio(0);
        }
        __builtin_amdgcn_s_barrier();          // buf[cur] reads done before overwrite
        cur ^= 1;
    }

    if (nc == 1) {
        const float inv = 1.0f / lsum;
        __bf16* op = Ob + (size_t)(b*SEQ + qw0 + l16) * DIM + h*HDIM;
#pragma unroll
        for (int d = 0; d < 8; ++d) {
            bf16x4 pk;
#pragma unroll
            for (int r = 0; r < 4; ++r) pk[r] = (__bf16)(o[d][r] * inv);
            *(bf16x4*)(op + d*16 + lh*4) = pk;
        }
    } else {
        const int pid = bh * NCHUNK_TOT + cstart + chunk;
        const int lq  = wv * 16 + l16;
        __bf16* pop = po + ((size_t)pid * 64 + lq) * HDIM;
#pragma unroll
        for (int d = 0; d < 8; ++d) {
            bf16x4 pk;
#pragma unroll
            for (int r = 0; r < 4; ++r) pk[r] = (__bf16)o[d][r];
            *(bf16x4*)(pop + d*16 + lh*4) = pk;
        }
        if (lh == 0) {
            pm[(size_t)pid * 64 + lq] = mx;
            pl[(size_t)pid * 64 + lq] = lsum;
        }
    }
}

// ---------------- merge partials: tiles 7..31 (nc in {2,3,4}) ----------------
__global__ __launch_bounds__(256) void merge_kernel(const __bf16* __restrict__ po,
    const float* __restrict__ pm, const float* __restrict__ pl,
    __bf16* __restrict__ Ob) {
    const int id = blockIdx.x;             // 24 bh x 25 tiles (7..31)
    const int bh = id / 25;
    const int tile = 7 + id % 25;
    int cstart, nc;
    if      (tile < 15) { cstart = 7  + (tile-7)*2;   nc = 2; }
    else if (tile < 23) { cstart = 23 + (tile-15)*3;  nc = 3; }
    else                { cstart = 47 + (tile-23)*4;  nc = 4; }
    const int b = bh / HEADS, h = bh - b * HEADS;
    const int lq = threadIdx.x >> 2;       // 0..63
    const int d0 = (threadIdx.x & 3) * 32;
    const size_t pb = (size_t)bh * NCHUNK_TOT + cstart;
    float M = -INFINITY;
    for (int cc = 0; cc < nc; ++cc) M = fmaxf(M, pm[(pb + cc) * 64 + lq]);
    float L = 0.f, w[4] = {0.f, 0.f, 0.f, 0.f};
    for (int cc = 0; cc < nc; ++cc) {
        w[cc] = exp2f(pm[(pb + cc) * 64 + lq] - M);
        L += w[cc] * pl[(pb + cc) * 64 + lq];
    }
    const float invL = 1.0f / L;
    __bf16* op = Ob + (size_t)(b*SEQ + tile*64 + lq) * DIM + h*HDIM;
#pragma unroll
    for (int d = 0; d < 32; d += 8) {
        float acc[8] = {};
        for (int cc = 0; cc < nc; ++cc) {
            bf16x8 v = *(const bf16x8*)&po[((pb + cc) * 64 + lq) * HDIM + d0 + d];
            const float wc = w[cc];
#pragma unroll
            for (int e = 0; e < 8; ++e) acc[e] += wc * (float)v[e];
        }
        bf16x8 ov;
#pragma unroll
        for (int e = 0; e < 8; ++e) ov[e] = (__bf16)(acc[e] * invL);
        *(bf16x8*)(op + d0 + d) = ov;
    }
}

// ---------------- launch ----------------
extern "C" void kernel_launch(void* const* d_in, const int* in_sizes, int n_in,
                              void* d_out, int out_size, void* d_ws, size_t ws_size,
                              hipStream_t stream) {
    const float* x  = (const float*)d_in[0];
    const float* Wq = (const float*)d_in[1];
    const float* bq = (const float*)d_in[2];
    const float* Wk = (const float*)d_in[3];
    const float* bk = (const float*)d_in[4];
    const float* Wv = (const float*)d_in[5];
    const float* bv = (const float*)d_in[6];
    const float* Wo = (const float*)d_in[7];
    const float* bo = (const float*)d_in[8];

    char* p = (char*)d_ws;
    const size_t SZ_X = (size_t)MTOT * DIM * 2;        // 12.6 MB
    const size_t SZ_W = (size_t)DIM * DIM * 2;         // 1.18 MB
    __bf16* xb   = (__bf16*)p; p += SZ_X;              // also reused as Ob
    __bf16* Wcat = (__bf16*)p; p += 3 * SZ_W;          // [2304][768]
    __bf16* Wto  = (__bf16*)p; p += SZ_W;
    __bf16* Qb   = (__bf16*)p; p += SZ_X;
    __bf16* Kb   = (__bf16*)p; p += SZ_X;
    __bf16* Vt   = (__bf16*)p; p += SZ_X;
    __bf16* Ob   = xb;                                 // alias: xb dead after gemm_qkv

    const size_t SZ_PO = (size_t)24 * NCHUNK_TOT * 64 * HDIM * 2;  // 32.6 MB
    const size_t SZ_PM = (size_t)24 * NCHUNK_TOT * 64 * 4;         // 0.51 MB
    __bf16* po  = (__bf16*)p;           p += SZ_PO;
    float*  pmv = (float*)p;            p += SZ_PM;
    float*  plv = (float*)p;

    prep_kernel<<<6144 + 2304, 256, 0, stream>>>(
        x, xb, Wq, Wk, Wv, Wo,
        Wcat, Wcat + (size_t)DIM*DIM, Wcat + (size_t)2*DIM*DIM, Wto);

    gemm_qkv<<<(MTOT/128) * (2304/128), 256, 0, stream>>>(xb, Wcat, bq, bk, bv, Qb, Kb, Vt);

    attn_kernel<<<8 * 3 * NCHUNK_TOT, 256, 0, stream>>>(Qb, Kb, Vt, po, pmv, plv, Ob);
    merge_kernel<<<24 * 25, 256, 0, stream>>>(po, pmv, plv, Ob);

    gemm_out<<<(MTOT/128) * (DIM/128), 256, 0, stream>>>(Ob, Wto, bo, (float*)d_out);
}

// Round 14
// 163.344 us; speedup vs baseline: 1.3181x; 1.0310x over previous
//
#include <hip/hip_runtime.h>
#include <math.h>

#define HEADS 6
#define SEQ   2048
#define DIM   768
#define HDIM  128
#define BATCH 4
#define MTOT  (BATCH*SEQ)   // 8192
#define NKV   (SEQ/32)      // 64
#define NCHUNK_TOT 83       // sum over 32 tiles of ceil(min(2t+3,64)/16)

typedef float  f32x4   __attribute__((ext_vector_type(4)));
typedef __bf16 bf16x8  __attribute__((ext_vector_type(8)));
typedef __bf16 bf16x4  __attribute__((ext_vector_type(4)));
typedef float  f32x4v  __attribute__((ext_vector_type(4)));

typedef __attribute__((address_space(3))) void lds_v;
typedef __attribute__((address_space(1))) void gbl_v;

__device__ __forceinline__ f32x4 mfma16(bf16x8 a, bf16x8 b, f32x4 c) {
    return __builtin_amdgcn_mfma_f32_16x16x32_bf16(a, b, c, 0, 0, 0);
}
__device__ __forceinline__ unsigned int bperm(int srclane, unsigned int v) {
    return (unsigned int)__builtin_amdgcn_ds_bpermute(srclane << 2, (int)v);
}
__device__ __forceinline__ unsigned int cvtpk(float lo, float hi) {
    unsigned int r;
    asm("v_cvt_pk_bf16_f32 %0, %1, %2" : "=v"(r) : "v"(lo), "v"(hi));
    return r;
}

// ------- fused prepass: cast x (f32->bf16) + transpose 4 weights -> bf16 -------
__global__ __launch_bounds__(256) void prep_kernel(
    const float* __restrict__ x, __bf16* __restrict__ xb,
    const float* __restrict__ W0, const float* __restrict__ W1,
    const float* __restrict__ W2, const float* __restrict__ W3,
    __bf16* __restrict__ T0, __bf16* __restrict__ T1,
    __bf16* __restrict__ T2, __bf16* __restrict__ T3) {
    __shared__ float tile[32][33];
    if (blockIdx.x < 6144) {
        int i = (blockIdx.x * 256 + threadIdx.x) * 4;
        f32x4v v = *(const f32x4v*)(x + i);
        bf16x4 o;
        o[0] = (__bf16)v[0]; o[1] = (__bf16)v[1];
        o[2] = (__bf16)v[2]; o[3] = (__bf16)v[3];
        *(bf16x4*)(xb + i) = o;
        return;
    }
    const int bid = blockIdx.x - 6144;          // 0..2303
    const int z = bid / 576, r = bid % 576;
    const int bx = r % 24, by = r / 24;
    const float* W; __bf16* T;
    if      (z == 0) { W = W0; T = T0; }
    else if (z == 1) { W = W1; T = T1; }
    else if (z == 2) { W = W2; T = T2; }
    else             { W = W3; T = T3; }
    int n0 = bx * 32, k0 = by * 32;
    int tx = threadIdx.x & 31, ty = threadIdx.x >> 5;
#pragma unroll
    for (int i = 0; i < 4; ++i)
        tile[ty + i*8][tx] = W[(size_t)(k0 + ty + i*8) * DIM + n0 + tx];
    __syncthreads();
#pragma unroll
    for (int i = 0; i < 4; ++i)
        T[(size_t)(n0 + ty + i*8) * DIM + k0 + tx] = (__bf16)tile[tx][ty + i*8];
}

// ============ GEMM core: triple-buffered LDS, 2-ahead prefetch, vmcnt(4) ============
#define GEMM_PIPE(A_PTR, B_PTR, NKSTEP)                                           \
    __shared__ __align__(16) __bf16 As[3][128 * 32];                              \
    __shared__ __align__(16) __bf16 Bs[3][128 * 32];                              \
    const int tid  = threadIdx.x;                                                 \
    const int wave = tid >> 6, lane = tid & 63;                                   \
    const int l16  = lane & 15, lh = lane >> 4;                                   \
    const int wr = wave >> 1, wc = wave & 1;                                      \
    f32x4 acc[4][4] = {};                                                         \
    auto stage = [&](int buf, int step) {                                         \
        const int k0 = step * 32;                                                 \
        _Pragma("unroll")                                                         \
        for (int ci = 0; ci < 4; ++ci) {                                          \
            int c = wave * 4 + ci;                                                \
            int t = c & 7;                                                        \
            int e = (t * 64 + lane) * 8;                                          \
            int r = e >> 5, kk = e & 31;                                          \
            const __bf16* gp = (c < 8) ? ((A_PTR) + (size_t)(m0 + r) * DIM + k0 + kk) \
                                       : ((B_PTR) + (size_t)(n0 + r) * DIM + k0 + kk); \
            __bf16* lp = (c < 8 ? As[buf] : Bs[buf]) + t * 512;                   \
            __builtin_amdgcn_global_load_lds((const gbl_v*)gp, (lds_v*)lp, 16, 0, 0); \
        }                                                                         \
    };                                                                            \
    stage(0, 0); stage(1, 1);                                                     \
    asm volatile("s_waitcnt vmcnt(4)" ::: "memory");                              \
    __builtin_amdgcn_s_barrier();                                                 \
    for (int t = 0; t < (NKSTEP); ++t) {                                          \
        const int cur = t % 3;                                                    \
        if (t + 2 < (NKSTEP)) stage((t + 2) % 3, t + 2);                          \
        bf16x8 af[4], bfr[4];                                                     \
        _Pragma("unroll")                                                         \
        for (int i = 0; i < 4; ++i)                                               \
            af[i] = *(const bf16x8*)&As[cur][(wr*64 + i*16 + l16) * 32 + lh*8];   \
        _Pragma("unroll")                                                         \
        for (int j = 0; j < 4; ++j)                                               \
            bfr[j] = *(const bf16x8*)&Bs[cur][(wc*64 + j*16 + l16) * 32 + lh*8];  \
        __builtin_amdgcn_s_setprio(1);                                            \
        _Pragma("unroll")                                                         \
        for (int i = 0; i < 4; ++i)                                               \
            _Pragma("unroll")                                                     \
            for (int j = 0; j < 4; ++j)                                           \
                acc[i][j] = mfma16(af[i], bfr[j], acc[i][j]);                     \
        __builtin_amdgcn_s_setprio(0);                                            \
        if (t + 2 < (NKSTEP))      asm volatile("s_waitcnt vmcnt(4)" ::: "memory"); \
        else if (t + 1 < (NKSTEP)) asm volatile("s_waitcnt vmcnt(0)" ::: "memory"); \
        __builtin_amdgcn_s_barrier();                                             \
    }

// ---------------- fused QKV GEMM: [8192,768] @ Wcat[2304,768]^T ----------------
__global__ __launch_bounds__(256) void gemm_qkv(const __bf16* __restrict__ A,
                                                const __bf16* __restrict__ Wcat,
                                                const float* __restrict__ bq,
                                                const float* __restrict__ bk,
                                                const float* __restrict__ bv,
                                                __bf16* __restrict__ Qb,
                                                __bf16* __restrict__ Kb,
                                                __bf16* __restrict__ Vt) {
    constexpr int NWG = (MTOT/128) * (2304/128);    // 1152, %8==0
    const int swz = (blockIdx.x & 7) * (NWG >> 3) + (blockIdx.x >> 3);
    const int bn = swz % (2304 / 128), bm = swz / (2304 / 128);
    const int m0 = bm * 128, n0 = bn * 128;
    GEMM_PIPE(A, Wcat, 24)

    const int sel = n0 / DIM;                 // 0=Q 1=K 2=V (block-uniform)
    const float* bias = sel == 0 ? bq : (sel == 1 ? bk : bv);
#pragma unroll
    for (int i = 0; i < 4; ++i) {
        int row = m0 + wr*64 + i*16 + lh*4;
#pragma unroll
        for (int j = 0; j < 4; ++j) {
            int col  = n0 + wc*64 + j*16 + l16;
            int lcol = col - sel * DIM;
            float bvv = bias[lcol];
            if (sel < 2) {
                __bf16* o = (sel == 0) ? Qb : Kb;
#pragma unroll
                for (int r = 0; r < 4; ++r)
                    o[(size_t)(row + r) * DIM + lcol] = (__bf16)(acc[i][j][r] + bvv);
            } else {
                int bb = row >> 11, ll = row & (SEQ - 1);
                int hh = lcol >> 7, dd = lcol & (HDIM - 1);
                bf16x4 pk;
#pragma unroll
                for (int r = 0; r < 4; ++r) pk[r] = (__bf16)(acc[i][j][r] + bvv);
                *(bf16x4*)&Vt[((size_t)((bb*HEADS + hh) * HDIM + dd)) * SEQ + ll] = pk;
            }
        }
    }
}

// ---------------- out-proj GEMM: [8192,768] @ Wto[768,768]^T -> f32 ----------------
__global__ __launch_bounds__(256) void gemm_out(const __bf16* __restrict__ A,
                                                const __bf16* __restrict__ Bt,
                                                const float* __restrict__ bias,
                                                float* __restrict__ outp) {
    constexpr int NWG = (MTOT/128) * (DIM/128);     // 384, %8==0
    const int swz = (blockIdx.x & 7) * (NWG >> 3) + (blockIdx.x >> 3);
    const int bn = swz % (DIM / 128), bm = swz / (DIM / 128);
    const int m0 = bm * 128, n0 = bn * 128;
    GEMM_PIPE(A, Bt, 24)

#pragma unroll
    for (int i = 0; i < 4; ++i) {
        int row = m0 + wr*64 + i*16 + lh*4;
#pragma unroll
        for (int j = 0; j < 4; ++j) {
            int col = n0 + wc*64 + j*16 + l16;
            float bv = bias[col];
#pragma unroll
            for (int r = 0; r < 4; ++r)
                outp[(size_t)(row + r) * DIM + col] = acc[i][j][r] + bv;
        }
    }
}

// ---------------- flash attention: r13 structure + VALU diet ----------------
// Work quantum = (bh, tile, chunk), chunk <= 16 k-blocks, LPT order, XCD-pinned.
// Inner loop = r3-verified 16x16 path with two local changes:
//   (1) defer-max (THR=8 log2): skip O-rescale while max growth <= 8 - the
//       32-mul rescale now fires ~never on this data.
//   (2) P packing via v_cvt_pk_bf16_f32 (1 op/word vs ~4).
__global__ __launch_bounds__(256, 3) void attn_kernel(
    const __bf16* __restrict__ Q, const __bf16* __restrict__ K,
    const __bf16* __restrict__ Vt,
    __bf16* __restrict__ po, float* __restrict__ pm, float* __restrict__ pl,
    __bf16* __restrict__ Ob) {
    __shared__ __align__(16) __bf16 Ks[2][32 * 128];
    __shared__ __align__(16) __bf16 Vs[2][128 * 32];
    const int lane = threadIdx.x & 63, wv = threadIdx.x >> 6;
    const int l16 = lane & 15, lh = lane >> 4;
    const int id  = blockIdx.x;
    const int xcd = id & 7;
    const int idx = id >> 3;
    const int bh_l = idx % 3;
    const int ci = (NCHUNK_TOT - 1) - idx / 3;      // LPT: heavy chunks first
    int tile, chunk;
    if      (ci < 7)  { tile = ci;                chunk = 0;          }
    else if (ci < 23) { tile = 7  + (ci-7)/2;     chunk = (ci-7)&1;   }
    else if (ci < 47) { tile = 15 + (ci-23)/3;    chunk = (ci-23)%3;  }
    else              { tile = 23 + (ci-47)/4;    chunk = (ci-47)&3;  }
    const int cstart = ci - chunk;
    const int bh = xcd + 8 * bh_l;
    const int b = bh / HEADS, h = bh - b * HEADS;
    const int qw0 = tile * 64 + wv * 16;
    const int nkb = min(2 * tile + 3, NKV);
    const int nc  = (nkb + 15) >> 4;
    const int lo  = chunk * 16;
    const int cnt = min(lo + 16, nkb) - lo;
    const float qs = 0.12751674770951932f;  // 1/sqrt(128) * log2(e)

    bf16x8 qf[4];
    {
        const __bf16* qp = Q + (size_t)(b*SEQ + qw0 + l16) * DIM + h*HDIM + lh*8;
#pragma unroll
        for (int kk = 0; kk < 4; ++kk) {
            bf16x8 v = *(const bf16x8*)(qp + kk*32);
            bf16x8 sv;
#pragma unroll
            for (int e = 0; e < 8; ++e) sv[e] = (__bf16)((float)v[e] * qs);
            qf[kk] = sv;
        }
    }

    const __bf16* kgb = K  + (size_t)(b*SEQ) * DIM + h*HDIM;
    const __bf16* vgb = Vt + (size_t)bh * HDIM * SEQ;

    auto stage = [&](int buf, int kb) {
        const int kbase = kb * 32;
#pragma unroll
        for (int s = 0; s < 4; ++s) {
            const int j = wv * 4 + s;          // wave-uniform
            if (j < 8) {
                const int row = j * 4 + (lane >> 4);
                const int c16 = (lane & 15) ^ (row & 7);      // pre-swizzled source
                const __bf16* gp = kgb + (size_t)(kbase + row) * DIM + c16 * 8;
                __builtin_amdgcn_global_load_lds((const gbl_v*)gp,
                    (lds_v*)&Ks[buf][j * 512], 16, 0, 0);
            } else {
                const int jj = j - 8;
                const int row = jj * 16 + (lane >> 2);
                const int c16 = (lane & 3) ^ ((row >> 1) & 3);
                const __bf16* gp = vgb + (size_t)row * SEQ + kbase + c16 * 8;
                __builtin_amdgcn_global_load_lds((const gbl_v*)gp,
                    (lds_v*)&Vs[buf][jj * 512], 16, 0, 0);
            }
        }
    };

    f32x4 o[8] = {};
    float mx = -INFINITY, lsum = 0.f;

    stage(0, lo);
    asm volatile("s_waitcnt vmcnt(0)" ::: "memory");
    __builtin_amdgcn_s_barrier();

    int cur = 0;
    for (int i = 0; i < cnt; ++i) {
        const int kb = lo + i;
        const int kbase = kb * 32;
        const bool more = (i + 1 < cnt);       // block-uniform
        if (more) {
            stage(cur ^ 1, kb + 1);
            asm volatile("s_waitcnt vmcnt(4)" ::: "memory");  // prev stage done, next in flight
        } else {
            asm volatile("s_waitcnt vmcnt(0)" ::: "memory");
        }
        __builtin_amdgcn_s_barrier();          // buf[cur] valid for all waves

        if (kbase <= qw0 + 16) {               // wave-uniform activity test
            bf16x8 kfA[4], kfB[4];
#pragma unroll
            for (int kk = 0; kk < 4; ++kk) {
                const int ca = (kk*4 + lh) ^ (l16 & 7);
                kfA[kk] = *(const bf16x8*)&Ks[cur][l16 * 128 + ca * 8];
                const int rb = 16 + l16;
                const int cb = (kk*4 + lh) ^ (rb & 7);
                kfB[kk] = *(const bf16x8*)&Ks[cur][rb * 128 + cb * 8];
            }
            f32x4 sA = {}, sB = {};
            __builtin_amdgcn_s_setprio(1);
#pragma unroll
            for (int kk = 0; kk < 4; ++kk) {
                sA = mfma16(kfA[kk], qf[kk], sA);
                sB = mfma16(kfB[kk], qf[kk], sB);
            }
            __builtin_amdgcn_s_setprio(0);
            const int q = qw0 + l16;
            float p[8];
#pragma unroll
            for (int r = 0; r < 4; ++r) { p[r] = sA[r]; p[r+4] = sB[r]; }
            if (kbase + 30 > qw0) {            // diagonal: apply causal mask
#pragma unroll
                for (int r = 0; r < 4; ++r) {
                    const int key = kbase + lh*4 + r;
                    if (key      > q + 1) p[r]   = -INFINITY;
                    if (key + 16 > q + 1) p[r+4] = -INFINITY;
                }
            }
            float m0 = p[0];
#pragma unroll
            for (int t2 = 1; t2 < 8; ++t2) m0 = fmaxf(m0, p[t2]);
            m0 = fmaxf(m0, __shfl_xor(m0, 16));
            m0 = fmaxf(m0, __shfl_xor(m0, 32));
            // defer-max: skip O-rescale while per-q growth <= 8 (log2 domain)
            const bool defer = __all(m0 <= mx + 8.f && mx > -3e38f);
            if (!defer) {
                const float mnew = fmaxf(mx, m0);
                const float resc = (mx < mnew) ? exp2f(mx - mnew) : 1.0f;  // -inf guard
                lsum *= resc;
#pragma unroll
                for (int d = 0; d < 8; ++d)
#pragma unroll
                    for (int r = 0; r < 4; ++r) o[d][r] *= resc;
                mx = mnew;
            }
            const float mref = (mx == -INFINITY) ? 0.f : mx;   // all-masked guard
#pragma unroll
            for (int t2 = 0; t2 < 8; ++t2) p[t2] = exp2f(p[t2] - mref);
            float rs = 0.f;
#pragma unroll
            for (int t2 = 0; t2 < 8; ++t2) rs += p[t2];
            rs += __shfl_xor(rs, 16);
            rs += __shfl_xor(rs, 32);
            lsum += rs;
            unsigned int w0 = cvtpk(p[0], p[1]);
            unsigned int w1 = cvtpk(p[2], p[3]);
            unsigned int w2 = cvtpk(p[4], p[5]);
            unsigned int w3 = cvtpk(p[6], p[7]);
            const int s0l = l16 + ((lh & 1) << 5);
            unsigned int A0 = bperm(s0l,      w0), A1 = bperm(s0l,      w1);
            unsigned int A2 = bperm(s0l,      w2), A3 = bperm(s0l,      w3);
            unsigned int B0 = bperm(s0l + 16, w0), B1 = bperm(s0l + 16, w1);
            unsigned int B2 = bperm(s0l + 16, w2), B3 = bperm(s0l + 16, w3);
            const bool hi = (lh >= 2);
            union { unsigned int u[4]; bf16x8 v; } pu;
            pu.u[0] = hi ? A2 : A0;
            pu.u[1] = hi ? A3 : A1;
            pu.u[2] = hi ? B2 : B0;
            pu.u[3] = hi ? B3 : B1;
            const bf16x8 pf = pu.v;
            __builtin_amdgcn_s_setprio(1);
#pragma unroll
            for (int d = 0; d < 8; ++d) {
                const int row = d * 16 + l16;
                const int cv = lh ^ ((row >> 1) & 3);
                bf16x8 vf = *(const bf16x8*)&Vs[cur][row * 32 + cv * 8];
                o[d] = mfma16(vf, pf, o[d]);
            }
            __builtin_amdgcn_s_setprio(0);
        }
        __builtin_amdgcn_s_barrier();          // buf[cur] reads done before overwrite
        cur ^= 1;
    }

    if (nc == 1) {
        const float inv = 1.0f / lsum;
        __bf16* op = Ob + (size_t)(b*SEQ + qw0 + l16) * DIM + h*HDIM;
#pragma unroll
        for (int d = 0; d < 8; ++d) {
            bf16x4 pk;
#pragma unroll
            for (int r = 0; r < 4; ++r) pk[r] = (__bf16)(o[d][r] * inv);
            *(bf16x4*)(op + d*16 + lh*4) = pk;
        }
    } else {
        const int pid = bh * NCHUNK_TOT + cstart + chunk;
        const int lq  = wv * 16 + l16;
        __bf16* pop = po + ((size_t)pid * 64 + lq) * HDIM;
#pragma unroll
        for (int d = 0; d < 8; ++d) {
            bf16x4 pk;
#pragma unroll
            for (int r = 0; r < 4; ++r) pk[r] = (__bf16)o[d][r];
            *(bf16x4*)(pop + d*16 + lh*4) = pk;
        }
        if (lh == 0) {
            pm[(size_t)pid * 64 + lq] = mx;
            pl[(size_t)pid * 64 + lq] = lsum;
        }
    }
}

// ---------------- merge partials: tiles 7..31 (nc in {2,3,4}) ----------------
__global__ __launch_bounds__(256) void merge_kernel(const __bf16* __restrict__ po,
    const float* __restrict__ pm, const float* __restrict__ pl,
    __bf16* __restrict__ Ob) {
    const int id = blockIdx.x;             // 24 bh x 25 tiles (7..31)
    const int bh = id / 25;
    const int tile = 7 + id % 25;
    int cstart, nc;
    if      (tile < 15) { cstart = 7  + (tile-7)*2;   nc = 2; }
    else if (tile < 23) { cstart = 23 + (tile-15)*3;  nc = 3; }
    else                { cstart = 47 + (tile-23)*4;  nc = 4; }
    const int b = bh / HEADS, h = bh - b * HEADS;
    const int lq = threadIdx.x >> 2;       // 0..63
    const int d0 = (threadIdx.x & 3) * 32;
    const size_t pb = (size_t)bh * NCHUNK_TOT + cstart;
    float M = -INFINITY;
    for (int cc = 0; cc < nc; ++cc) M = fmaxf(M, pm[(pb + cc) * 64 + lq]);
    float L = 0.f, w[4] = {0.f, 0.f, 0.f, 0.f};
    for (int cc = 0; cc < nc; ++cc) {
        w[cc] = exp2f(pm[(pb + cc) * 64 + lq] - M);
        L += w[cc] * pl[(pb + cc) * 64 + lq];
    }
    const float invL = 1.0f / L;
    __bf16* op = Ob + (size_t)(b*SEQ + tile*64 + lq) * DIM + h*HDIM;
#pragma unroll
    for (int d = 0; d < 32; d += 8) {
        float acc[8] = {};
        for (int cc = 0; cc < nc; ++cc) {
            bf16x8 v = *(const bf16x8*)&po[((pb + cc) * 64 + lq) * HDIM + d0 + d];
            const float wc = w[cc];
#pragma unroll
            for (int e = 0; e < 8; ++e) acc[e] += wc * (float)v[e];
        }
        bf16x8 ov;
#pragma unroll
        for (int e = 0; e < 8; ++e) ov[e] = (__bf16)(acc[e] * invL);
        *(bf16x8*)(op + d0 + d) = ov;
    }
}

// ---------------- launch ----------------
extern "C" void kernel_launch(void* const* d_in, const int* in_sizes, int n_in,
                              void* d_out, int out_size, void* d_ws, size_t ws_size,
                              hipStream_t stream) {
    const float* x  = (const float*)d_in[0];
    const float* Wq = (const float*)d_in[1];
    const float* bq = (const float*)d_in[2];
    const float* Wk = (const float*)d_in[3];
    const float* bk = (const float*)d_in[4];
    const float* Wv = (const float*)d_in[5];
    const float* bv = (const float*)d_in[6];
    const float* Wo = (const float*)d_in[7];
    const float* bo = (const float*)d_in[8];

    char* p = (char*)d_ws;
    const size_t SZ_X = (size_t)MTOT * DIM * 2;        // 12.6 MB
    const size_t SZ_W = (size_t)DIM * DIM * 2;         // 1.18 MB
    __bf16* xb   = (__bf16*)p; p += SZ_X;              // also reused as Ob
    __bf16* Wcat = (__bf16*)p; p += 3 * SZ_W;          // [2304][768]
    __bf16* Wto  = (__bf16*)p; p += SZ_W;
    __bf16* Qb   = (__bf16*)p; p += SZ_X;
    __bf16* Kb   = (__bf16*)p; p += SZ_X;
    __bf16* Vt   = (__bf16*)p; p += SZ_X;
    __bf16* Ob   = xb;                                 // alias: xb dead after gemm_qkv

    const size_t SZ_PO = (size_t)24 * NCHUNK_TOT * 64 * HDIM * 2;  // 32.6 MB
    const size_t SZ_PM = (size_t)24 * NCHUNK_TOT * 64 * 4;         // 0.51 MB
    __bf16* po  = (__bf16*)p;           p += SZ_PO;
    float*  pmv = (float*)p;            p += SZ_PM;
    float*  plv = (float*)p;

    prep_kernel<<<6144 + 2304, 256, 0, stream>>>(
        x, xb, Wq, Wk, Wv, Wo,
        Wcat, Wcat + (size_t)DIM*DIM, Wcat + (size_t)2*DIM*DIM, Wto);

    gemm_qkv<<<(MTOT/128) * (2304/128), 256, 0, stream>>>(xb, Wcat, bq, bk, bv, Qb, Kb, Vt);

    attn_kernel<<<8 * 3 * NCHUNK_TOT, 256, 0, stream>>>(Qb, Kb, Vt, po, pmv, plv, Ob);
    merge_kernel<<<24 * 25, 256, 0, stream>>>(po, pmv, plv, Ob);

    gemm_out<<<(MTOT/128) * (DIM/128), 256, 0, stream>>>(Ob, Wto, bo, (float*)d_out);
}